// Round 1
// baseline (2804.230 us; speedup 1.0000x reference)
//
#include <hip/hip_runtime.h>
#include <cstdint>
#include <cstddef>

#define D_MODEL 768
#define D_STATE 16
#define D_CONV  4
#define D_INNER 1536
#define DT_RANK 48
#define NB      4
#define NL      2048
#define NROWS   (NB * NL)   // 8192
#define EPS     1e-5f

__device__ __forceinline__ float siluf(float x) { return x / (1.f + __expf(-x)); }
__device__ __forceinline__ float softplusf(float x) {
    return x > 20.f ? x : log1pf(__expf(x));
}

// ---------------------------------------------------------------- RMSNorm ---
__global__ __launch_bounds__(256) void rmsnorm_k(const float* __restrict__ seq,
                                                 const float* __restrict__ w,
                                                 float* __restrict__ out) {
    int row = blockIdx.x;
    const float* x = seq + (size_t)row * D_MODEL;
    float* o = out + (size_t)row * D_MODEL;
    int t = threadIdx.x;
    float v0 = x[t], v1 = x[t + 256], v2 = x[t + 512];
    float ss = v0 * v0 + v1 * v1 + v2 * v2;
#pragma unroll
    for (int off = 32; off; off >>= 1) ss += __shfl_down(ss, off, 64);
    __shared__ float parts[4];
    if ((t & 63) == 0) parts[t >> 6] = ss;
    __syncthreads();
    float tot = parts[0] + parts[1] + parts[2] + parts[3];
    float rs = rsqrtf(tot / (float)D_MODEL + EPS);
    o[t]       = v0 * rs * w[t];
    o[t + 256] = v1 * rs * w[t + 256];
    o[t + 512] = v2 * rs * w[t + 512];
}

// ------------------------------------------------------------ tiled GEMM ----
// C[M,N] = A[M,K] @ B[K,N]; row-major with leading dims.
// EPI 0: plain store. EPI 1: softplus(v + aux[col]). EPI 2: v + aux[row*ldc+col].
template <int EPI>
__global__ __launch_bounds__(256) void gemm_k(const float* __restrict__ A,
                                              const float* __restrict__ B,
                                              float* __restrict__ C,
                                              int M, int N, int K,
                                              int lda, int ldb, int ldc,
                                              const float* __restrict__ aux) {
    __shared__ float As[16][64];
    __shared__ float Bs[16][64];
    const int tid = threadIdx.x;
    const int tx = tid & 15, ty = tid >> 4;
    const int bm = blockIdx.y * 64, bn = blockIdx.x * 64;
    float acc[4][4] = {};
    for (int k0 = 0; k0 < K; k0 += 16) {
#pragma unroll
        for (int i = 0; i < 4; i++) {
            int idx = tid + i * 256;
            int r = idx >> 4, kk = idx & 15;
            int gk = k0 + kk;
            As[kk][r] = (gk < K) ? A[(size_t)(bm + r) * lda + gk] : 0.f;
        }
#pragma unroll
        for (int i = 0; i < 4; i++) {
            int idx = tid + i * 256;
            int kk = idx >> 6, c = idx & 63;
            int gk = k0 + kk, gc = bn + c;
            Bs[kk][c] = (gk < K && gc < N) ? B[(size_t)gk * ldb + gc] : 0.f;
        }
        __syncthreads();
#pragma unroll
        for (int kk = 0; kk < 16; kk++) {
            float4 av = *reinterpret_cast<const float4*>(&As[kk][ty * 4]);
            float4 bv = *reinterpret_cast<const float4*>(&Bs[kk][tx * 4]);
            float a[4] = {av.x, av.y, av.z, av.w};
            float b[4] = {bv.x, bv.y, bv.z, bv.w};
#pragma unroll
            for (int i = 0; i < 4; i++)
#pragma unroll
                for (int j = 0; j < 4; j++) acc[i][j] += a[i] * b[j];
        }
        __syncthreads();
    }
#pragma unroll
    for (int i = 0; i < 4; i++) {
        int row = bm + ty * 4 + i;
#pragma unroll
        for (int j = 0; j < 4; j++) {
            int col = bn + tx * 4 + j;
            if (col < N) {
                float v = acc[i][j];
                if (EPI == 1) v = softplusf(v + aux[col]);
                else if (EPI == 2) v += aux[(size_t)row * ldc + col];
                C[(size_t)row * ldc + col] = v;
            }
        }
    }
}

// -------------------------------------------------- depthwise conv + SiLU ---
// xi[b,l,d] = silu(conv_b[d] + sum_k xz[b, l-3+k, d] * cw[d,k])
__global__ __launch_bounds__(256) void conv_silu_k(const float* __restrict__ xz,
                                                   const float* __restrict__ cw,
                                                   const float* __restrict__ cb,
                                                   float* __restrict__ xi) {
    int idx = blockIdx.x * 256 + threadIdx.x;
    if (idx >= NROWS * D_INNER) return;
    int d = idx % D_INNER;
    int row = idx / D_INNER;   // b*NL + l
    int l = row % NL;
    float w0 = cw[d * 4 + 0], w1 = cw[d * 4 + 1];
    float w2 = cw[d * 4 + 2], w3 = cw[d * 4 + 3];
    const float* base = xz + (size_t)row * (2 * D_INNER) + d;
    float acc = cb[d] + w3 * base[0];
    if (l >= 1) acc += w2 * base[-(ptrdiff_t)(2 * D_INNER)];
    if (l >= 2) acc += w1 * base[-(ptrdiff_t)(4 * D_INNER)];
    if (l >= 3) acc += w0 * base[-(ptrdiff_t)(6 * D_INNER)];
    xi[idx] = siluf(acc);
}

// -------------------------------------------------------- selective scan ----
// One 16-lane group per (b,d); lane s holds state s. y written over xi.
__global__ __launch_bounds__(256) void scan_k(const float* __restrict__ dtb,
                                              const float* __restrict__ xi,
                                              const float* __restrict__ xdbl,
                                              const float* __restrict__ xz,
                                              const float* __restrict__ A_log,
                                              const float* __restrict__ Dp,
                                              float* __restrict__ yf) {
    int g = blockIdx.x * 16 + (threadIdx.x >> 4);
    int s = threadIdx.x & 15;
    int b = g / D_INNER, d = g % D_INNER;
    float Av = -__expf(A_log[d * D_STATE + s]);
    float Dd = Dp[d];
    size_t rowbase = (size_t)b * NL;
    const float* dtp = dtb + rowbase * D_INNER + d;
    const float* xp  = xi + rowbase * D_INNER + d;
    const float* bp  = xdbl + rowbase * 80 + DT_RANK + s;
    const float* cp  = xdbl + rowbase * 80 + DT_RANK + D_STATE + s;
    const float* zp  = xz + rowbase * (size_t)(2 * D_INNER) + D_INNER + d;
    float* yp = yf + rowbase * D_INNER + d;
    float h = 0.f;
    float dt_n = dtp[0], x_n = xp[0], B_n = bp[0], C_n = cp[0];
    for (int l = 0; l < NL; l++) {
        float dt_c = dt_n, x_c = x_n, B_c = B_n, C_c = C_n;
        if (l + 1 < NL) {
            dt_n = dtp[(size_t)(l + 1) * D_INNER];
            x_n  = xp[(size_t)(l + 1) * D_INNER];
            B_n  = bp[(size_t)(l + 1) * 80];
            C_n  = cp[(size_t)(l + 1) * 80];
        }
        float dA = __expf(dt_c * Av);
        h = h * dA + (dt_c * x_c) * B_c;
        float p = h * C_c;
#pragma unroll
        for (int o = 8; o; o >>= 1) p += __shfl_xor(p, o, 16);
        if (s == 0) {
            float z = zp[(size_t)l * (2 * D_INNER)];
            yp[(size_t)l * D_INNER] = (p + Dd * x_c) * siluf(z);
        }
    }
}

// ----------------------------------------------------------------- launch ---
extern "C" void kernel_launch(void* const* d_in, const int* in_sizes, int n_in,
                              void* d_out, int out_size, void* d_ws, size_t ws_size,
                              hipStream_t stream) {
    const float* seq    = (const float*)d_in[0];
    const float* normw  = (const float*)d_in[1];
    const float* inpw   = (const float*)d_in[2];
    const float* convw  = (const float*)d_in[3];
    const float* convb  = (const float*)d_in[4];
    const float* xprojw = (const float*)d_in[5];
    const float* dtpw   = (const float*)d_in[6];
    const float* dtbias = (const float*)d_in[7];
    const float* Alog   = (const float*)d_in[8];
    const float* Dp     = (const float*)d_in[9];
    const float* outpw  = (const float*)d_in[10];
    float* out = (float*)d_out;

    float* xz    = (float*)d_ws;                              // 8192*3072
    float* xnorm = xz + (size_t)NROWS * 2 * D_INNER;          // 8192*768
    float* xi    = xnorm + (size_t)NROWS * D_MODEL;           // 8192*1536
    float* dt    = xi + (size_t)NROWS * D_INNER;              // 8192*1536
    float* xdbl  = dt + (size_t)NROWS * D_INNER;              // 8192*80

    // 1. RMSNorm
    rmsnorm_k<<<NROWS, 256, 0, stream>>>(seq, normw, xnorm);

    // 2. in_proj: xz = xnorm @ in_proj_w  [8192 x 3072, K=768]
    dim3 g1(2 * D_INNER / 64, NROWS / 64);
    gemm_k<0><<<g1, 256, 0, stream>>>(xnorm, inpw, xz, NROWS, 2 * D_INNER, D_MODEL,
                                      D_MODEL, 2 * D_INNER, 2 * D_INNER, nullptr);

    // 3. depthwise conv + SiLU -> xi
    conv_silu_k<<<(NROWS * D_INNER) / 256, 256, 0, stream>>>(xz, convw, convb, xi);

    // 4. x_proj: xdbl = xi @ x_proj_w  [8192 x 80, K=1536]
    dim3 g2((80 + 63) / 64, NROWS / 64);
    gemm_k<0><<<g2, 256, 0, stream>>>(xi, xprojw, xdbl, NROWS, 80, D_INNER,
                                      D_INNER, 80, 80, nullptr);

    // 5. dt_proj + softplus: dt = softplus(xdbl[:, :48] @ dt_proj_w + dt_bias)
    dim3 g3(D_INNER / 64, NROWS / 64);
    gemm_k<1><<<g3, 256, 0, stream>>>(xdbl, dtpw, dt, NROWS, D_INNER, DT_RANK,
                                      80, D_INNER, D_INNER, dtbias);

    // 6. selective scan (+ D*xi, * silu(z)); y overwrites xi in place
    scan_k<<<(NB * D_INNER) / 16, 256, 0, stream>>>(dt, xi, xdbl, xz, Alog, Dp, xi);

    // 7. out_proj + residual: out = y @ out_proj_w + seq
    dim3 g4(D_MODEL / 64, NROWS / 64);
    gemm_k<2><<<g4, 256, 0, stream>>>(xi, outpw, out, NROWS, D_MODEL, D_INNER,
                                      D_INNER, D_MODEL, D_MODEL, seq);
}

// Round 5
// 1017.531 us; speedup vs baseline: 2.7559x; 2.7559x over previous
//
#include <hip/hip_runtime.h>
#include <hip/hip_bf16.h>
#include <cstdint>
#include <cstddef>

#define D_MODEL 768
#define D_STATE 16
#define D_CONV  4
#define D_INNER 1536
#define DT_RANK 48
#define NB      4
#define NL      2048
#define NROWS   (NB * NL)   // 8192
#define EPS     1e-5f
#define NCHUNK  8
#define CHUNK   (NL / NCHUNK)   // 256

typedef __bf16 bf16x8 __attribute__((ext_vector_type(8)));
typedef float  f32x4  __attribute__((ext_vector_type(4)));
typedef __hip_bfloat16 bf16_t;

__device__ __forceinline__ float siluf(float x) { return x / (1.f + __expf(-x)); }
__device__ __forceinline__ float softplusf(float x) {
    return x > 20.f ? x : log1pf(__expf(x));
}
__device__ __forceinline__ void gload16(const void* g, void* l) {
    __builtin_amdgcn_global_load_lds((const __attribute__((address_space(1))) unsigned int*)g,
                                     (__attribute__((address_space(3))) unsigned int*)l, 16, 0, 0);
}

// ---------------------------------------------------------------- RMSNorm ---
// out is bf16 (feeds the MFMA in_proj GEMM)
__global__ __launch_bounds__(256) void rmsnorm_k(const float* __restrict__ seq,
                                                 const float* __restrict__ w,
                                                 bf16_t* __restrict__ out) {
    int row = blockIdx.x;
    const float* x = seq + (size_t)row * D_MODEL;
    bf16_t* o = out + (size_t)row * D_MODEL;
    int t = threadIdx.x;
    float v0 = x[t], v1 = x[t + 256], v2 = x[t + 512];
    float ss = v0 * v0 + v1 * v1 + v2 * v2;
#pragma unroll
    for (int off = 32; off; off >>= 1) ss += __shfl_down(ss, off, 64);
    __shared__ float parts[4];
    if ((t & 63) == 0) parts[t >> 6] = ss;
    __syncthreads();
    float tot = parts[0] + parts[1] + parts[2] + parts[3];
    float rs = rsqrtf(tot / (float)D_MODEL + EPS);
    o[t]       = __float2bfloat16(v0 * rs * w[t]);
    o[t + 256] = __float2bfloat16(v1 * rs * w[t + 256]);
    o[t + 512] = __float2bfloat16(v2 * rs * w[t + 512]);
}

// --------------------------------------------- weight transpose + convert ---
// w [K][N] fp32 -> wt [N][K] bf16
__global__ __launch_bounds__(256) void transpose_bf16_k(const float* __restrict__ w,
                                                        bf16_t* __restrict__ wt,
                                                        int K, int N) {
    __shared__ float t[32][33];
    int bx = blockIdx.x * 32, by = blockIdx.y * 32;
    int tx = threadIdx.x & 31, ty = threadIdx.x >> 5;  // 8 rows/pass
#pragma unroll
    for (int i = 0; i < 32; i += 8)
        t[ty + i][tx] = w[(size_t)(by + ty + i) * N + bx + tx];
    __syncthreads();
#pragma unroll
    for (int i = 0; i < 32; i += 8)
        wt[(size_t)(bx + ty + i) * K + by + tx] = __float2bfloat16(t[tx][ty + i]);
}

// ------------------------------------------------------- bf16 MFMA GEMM -----
// C[M,N] = A[M,K] * Bt[N,K]^T.  A,Bt bf16 row-major, K % 64 == 0.
// EPI 2: fp32 store of acc + aux[row*N+col].  EPI 3: bf16 store of acc.
template <int EPI>
__global__ __launch_bounds__(256) void mfma_gemm_k(const bf16_t* __restrict__ A,
                                                   const bf16_t* __restrict__ Bt,
                                                   void* __restrict__ Cv,
                                                   int M, int N, int K,
                                                   const float* __restrict__ aux) {
    __shared__ bf16_t As[128][64];
    __shared__ bf16_t Bs[128][64];
    const int tid = threadIdx.x;
    const int lane = tid & 63, wid = tid >> 6;
    const int bm = blockIdx.y * 128, bn = blockIdx.x * 128;
    const int wm = wid >> 1, wn = wid & 1;
    f32x4 acc[4][4] = {};
    for (int k0 = 0; k0 < K; k0 += 64) {
        // stage A,B tiles: 1024 16B-chunks each, linear LDS dest,
        // source column pre-swizzled (chunk c holds global chunk c^(r&7))
#pragma unroll
        for (int i = 0; i < 4; i++) {
            int idx = tid + i * 256;
            int r = idx >> 3, c = idx & 7;
            gload16(A + (size_t)(bm + r) * K + k0 + ((c ^ (r & 7)) << 3),
                    (bf16_t*)As + idx * 8);
        }
#pragma unroll
        for (int i = 0; i < 4; i++) {
            int idx = tid + i * 256;
            int r = idx >> 3, c = idx & 7;
            gload16(Bt + (size_t)(bn + r) * K + k0 + ((c ^ (r & 7)) << 3),
                    (bf16_t*)Bs + idx * 8);
        }
        asm volatile("s_waitcnt vmcnt(0)" ::: "memory");
        __syncthreads();
#pragma unroll
        for (int ks = 0; ks < 2; ks++) {
            bf16x8 af[4], bfr[4];
#pragma unroll
            for (int i = 0; i < 4; i++) {
                int row = wm * 64 + i * 16 + (lane & 15);
                int cl = ks * 4 + (lane >> 4);
                af[i] = *(const bf16x8*)(&As[row][(cl ^ (row & 7)) << 3]);
            }
#pragma unroll
            for (int j = 0; j < 4; j++) {
                int row = wn * 64 + j * 16 + (lane & 15);
                int cl = ks * 4 + (lane >> 4);
                bfr[j] = *(const bf16x8*)(&Bs[row][(cl ^ (row & 7)) << 3]);
            }
#pragma unroll
            for (int i = 0; i < 4; i++)
#pragma unroll
                for (int j = 0; j < 4; j++)
                    acc[i][j] = __builtin_amdgcn_mfma_f32_16x16x32_bf16(
                        af[i], bfr[j], acc[i][j], 0, 0, 0);
        }
        __syncthreads();
    }
    // epilogue: C/D layout col=lane&15, row=(lane>>4)*4+q
#pragma unroll
    for (int i = 0; i < 4; i++) {
#pragma unroll
        for (int j = 0; j < 4; j++) {
#pragma unroll
            for (int q = 0; q < 4; q++) {
                int row = bm + wm * 64 + i * 16 + (lane >> 4) * 4 + q;
                int col = bn + wn * 64 + j * 16 + (lane & 15);
                float v = acc[i][j][q];
                if (EPI == 2) {
                    ((float*)Cv)[(size_t)row * N + col] = v + aux[(size_t)row * N + col];
                } else {
                    ((bf16_t*)Cv)[(size_t)row * N + col] = __float2bfloat16(v);
                }
            }
        }
    }
}

// ----------------------------------------------------- fp32 tiled GEMM ------
// (kept for small x_proj / dt_proj).  EPI 0: plain. EPI 1: softplus(v+aux[col]).
// As stores XOR-swizzled to kill the 16-way write bank conflict.
template <int EPI>
__global__ __launch_bounds__(256) void gemm_k(const float* __restrict__ A,
                                              const float* __restrict__ B,
                                              float* __restrict__ C,
                                              int M, int N, int K,
                                              int lda, int ldb, int ldc,
                                              const float* __restrict__ aux) {
    __shared__ float As[16][64];
    __shared__ float Bs[16][64];
    const int tid = threadIdx.x;
    const int tx = tid & 15, ty = tid >> 4;
    const int bm = blockIdx.y * 64, bn = blockIdx.x * 64;
    float acc[4][4] = {};
    for (int k0 = 0; k0 < K; k0 += 16) {
#pragma unroll
        for (int i = 0; i < 4; i++) {
            int idx = tid + i * 256;
            int r = idx >> 4, kk = idx & 15;
            int gk = k0 + kk;
            As[kk][r ^ (kk << 2)] = (gk < K) ? A[(size_t)(bm + r) * lda + gk] : 0.f;
        }
#pragma unroll
        for (int i = 0; i < 4; i++) {
            int idx = tid + i * 256;
            int kk = idx >> 6, c = idx & 63;
            int gk = k0 + kk, gc = bn + c;
            Bs[kk][c] = (gk < K && gc < N) ? B[(size_t)gk * ldb + gc] : 0.f;
        }
        __syncthreads();
#pragma unroll
        for (int kk = 0; kk < 16; kk++) {
            float4 bv = *reinterpret_cast<const float4*>(&Bs[kk][tx * 4]);
            float b[4] = {bv.x, bv.y, bv.z, bv.w};
            float a[4];
#pragma unroll
            for (int i = 0; i < 4; i++) a[i] = As[kk][(ty * 4 + i) ^ (kk << 2)];
#pragma unroll
            for (int i = 0; i < 4; i++)
#pragma unroll
                for (int j = 0; j < 4; j++) acc[i][j] += a[i] * b[j];
        }
        __syncthreads();
    }
#pragma unroll
    for (int i = 0; i < 4; i++) {
        int row = bm + ty * 4 + i;
#pragma unroll
        for (int j = 0; j < 4; j++) {
            int col = bn + tx * 4 + j;
            if (col < N) {
                float v = acc[i][j];
                if (EPI == 1) v = softplusf(v + aux[col]);
                C[(size_t)row * ldc + col] = v;
            }
        }
    }
}

// -------------------------------------------------- depthwise conv + SiLU ---
__global__ __launch_bounds__(256) void conv_silu_k(const bf16_t* __restrict__ xz,
                                                   const float* __restrict__ cw,
                                                   const float* __restrict__ cb,
                                                   float* __restrict__ xi) {
    int idx = blockIdx.x * 256 + threadIdx.x;
    int d = idx % D_INNER;
    int row = idx / D_INNER;   // b*NL + l
    int l = row % NL;
    float w0 = cw[d * 4 + 0], w1 = cw[d * 4 + 1];
    float w2 = cw[d * 4 + 2], w3 = cw[d * 4 + 3];
    const bf16_t* base = xz + (size_t)row * (2 * D_INNER) + d;
    float acc = cb[d] + w3 * __bfloat162float(base[0]);
    if (l >= 1) acc += w2 * __bfloat162float(base[-(ptrdiff_t)(2 * D_INNER)]);
    if (l >= 2) acc += w1 * __bfloat162float(base[-(ptrdiff_t)(4 * D_INNER)]);
    if (l >= 3) acc += w0 * __bfloat162float(base[-(ptrdiff_t)(6 * D_INNER)]);
    xi[idx] = siluf(acc);
}

// --------------------------------------------------- scan phase A: carries --
// group (16 lanes) per (b, chunk, d): local scan with h0=0 -> h_end, sum(dt)
__global__ __launch_bounds__(256) void scanA_k(const float* __restrict__ dtb,
                                               const float* __restrict__ xi,
                                               const float* __restrict__ xdbl,
                                               const float* __restrict__ A_log,
                                               float* __restrict__ hend,
                                               float* __restrict__ dtsum) {
    int g = blockIdx.x * 16 + (threadIdx.x >> 4);
    int s = threadIdx.x & 15;
    int b = g / (NCHUNK * D_INNER);
    int rem = g % (NCHUNK * D_INNER);
    int c = rem / D_INNER, d = rem % D_INNER;
    float Av = -__expf(A_log[d * D_STATE + s]);
    size_t rowbase = (size_t)b * NL + (size_t)c * CHUNK;
    const float* dtp = dtb + rowbase * D_INNER + d;
    const float* xp  = xi + rowbase * D_INNER + d;
    const float* bp  = xdbl + rowbase * 80 + DT_RANK + s;
    float h = 0.f, dts = 0.f;
    float dt_n = dtp[0], x_n = xp[0], B_n = bp[0];
    for (int l = 0; l < CHUNK; l++) {
        float dt_c = dt_n, x_c = x_n, B_c = B_n;
        if (l + 1 < CHUNK) {
            dt_n = dtp[(size_t)(l + 1) * D_INNER];
            x_n  = xp[(size_t)(l + 1) * D_INNER];
            B_n  = bp[(size_t)(l + 1) * 80];
        }
        h = h * __expf(dt_c * Av) + (dt_c * x_c) * B_c;
        dts += dt_c;
    }
    size_t gi = (size_t)(b * NCHUNK + c) * D_INNER + d;
    hend[gi * 16 + s] = h;
    if (s == 0) dtsum[gi] = dts;
}

// --------------------------------------------- scan phase B: combine carries -
__global__ __launch_bounds__(256) void scanB_k(const float* __restrict__ hend,
                                               const float* __restrict__ dtsum,
                                               const float* __restrict__ A_log,
                                               float* __restrict__ carry) {
    int t = blockIdx.x * 256 + threadIdx.x;   // (b*D_INNER+d)*16+s
    int s = t & 15;
    int bd = t >> 4;
    int b = bd / D_INNER, d = bd % D_INNER;
    float Av = -__expf(A_log[d * D_STATE + s]);
    float h = 0.f;
    for (int c = 0; c < NCHUNK; c++) {
        size_t gi = (size_t)(b * NCHUNK + c) * D_INNER + d;
        carry[gi * 16 + s] = h;
        h = h * __expf(Av * dtsum[gi]) + hend[gi * 16 + s];
    }
}

// ------------------------------- scan phase C: full scan + gating, y -> bf16 -
__global__ __launch_bounds__(256) void scanC_k(const float* __restrict__ dtb,
                                               const float* __restrict__ xi,
                                               const float* __restrict__ xdbl,
                                               const bf16_t* __restrict__ xz,
                                               const float* __restrict__ A_log,
                                               const float* __restrict__ Dp,
                                               const float* __restrict__ carry,
                                               bf16_t* __restrict__ yb) {
    int g = blockIdx.x * 16 + (threadIdx.x >> 4);
    int s = threadIdx.x & 15;
    int b = g / (NCHUNK * D_INNER);
    int rem = g % (NCHUNK * D_INNER);
    int c = rem / D_INNER, d = rem % D_INNER;
    float Av = -__expf(A_log[d * D_STATE + s]);
    float Dd = Dp[d];
    size_t rowbase = (size_t)b * NL + (size_t)c * CHUNK;
    const float* dtp = dtb + rowbase * D_INNER + d;
    const float* xp  = xi + rowbase * D_INNER + d;
    const float* bp  = xdbl + rowbase * 80 + DT_RANK + s;
    const float* cp  = xdbl + rowbase * 80 + DT_RANK + D_STATE + s;
    const bf16_t* zp = xz + rowbase * (2 * D_INNER) + D_INNER + d;
    bf16_t* yp = yb + rowbase * D_INNER + d;
    size_t gi = (size_t)(b * NCHUNK + c) * D_INNER + d;
    float h = carry[gi * 16 + s];
    float dt_n = dtp[0], x_n = xp[0], B_n = bp[0], C_n = cp[0];
    for (int l = 0; l < CHUNK; l++) {
        float dt_c = dt_n, x_c = x_n, B_c = B_n, C_c = C_n;
        if (l + 1 < CHUNK) {
            dt_n = dtp[(size_t)(l + 1) * D_INNER];
            x_n  = xp[(size_t)(l + 1) * D_INNER];
            B_n  = bp[(size_t)(l + 1) * 80];
            C_n  = cp[(size_t)(l + 1) * 80];
        }
        h = h * __expf(dt_c * Av) + (dt_c * x_c) * B_c;
        float p = h * C_c;
#pragma unroll
        for (int o = 8; o; o >>= 1) p += __shfl_xor(p, o, 16);
        if (s == 0) {
            float z = __bfloat162float(zp[(size_t)l * (2 * D_INNER)]);
            yp[(size_t)l * D_INNER] = __float2bfloat16((p + Dd * x_c) * siluf(z));
        }
    }
}

// ----------------------------------------------------------------- launch ---
extern "C" void kernel_launch(void* const* d_in, const int* in_sizes, int n_in,
                              void* d_out, int out_size, void* d_ws, size_t ws_size,
                              hipStream_t stream) {
    const float* seq    = (const float*)d_in[0];
    const float* normw  = (const float*)d_in[1];
    const float* inpw   = (const float*)d_in[2];
    const float* convw  = (const float*)d_in[3];
    const float* convb  = (const float*)d_in[4];
    const float* xprojw = (const float*)d_in[5];
    const float* dtpw   = (const float*)d_in[6];
    const float* dtbias = (const float*)d_in[7];
    const float* Alog   = (const float*)d_in[8];
    const float* Dp     = (const float*)d_in[9];
    const float* outpw  = (const float*)d_in[10];
    float* out = (float*)d_out;

    float* ws = (float*)d_ws;
    float* xi    = ws;                       // 8192*1536           = 12582912 f
    float* dt    = xi + 12582912;            // 12582912 f
    float* xdbl  = dt + 12582912;            // 8192*80             = 655360 f
    float* hend  = xdbl + 655360;            // 4*8*1536*16         = 786432 f
    float* carry = hend + 786432;            // 786432 f
    float* dtsum = carry + 786432;           // 4*8*1536            = 49152 f
    bf16_t* xz_bf    = (bf16_t*)(dtsum + 49152);   // 8192*3072 = 25165824 bf16
    bf16_t* xnorm_bf = xz_bf + 25165824;           // 8192*768  = 6291456
    bf16_t* y_bf     = xnorm_bf + 6291456;         // 8192*1536 = 12582912
    bf16_t* w1t      = y_bf + 12582912;            // 3072*768  = 2359296
    bf16_t* w4t      = w1t + 2359296;              // 768*1536  = 1179648

    // 1. RMSNorm (bf16 out)
    rmsnorm_k<<<NROWS, 256, 0, stream>>>(seq, normw, xnorm_bf);

    // 1b. weight transposes -> bf16 [N][K]
    transpose_bf16_k<<<dim3(3072 / 32, 768 / 32), 256, 0, stream>>>(inpw, w1t, D_MODEL, 2 * D_INNER);
    transpose_bf16_k<<<dim3(768 / 32, 1536 / 32), 256, 0, stream>>>(outpw, w4t, D_INNER, D_MODEL);

    // 2. in_proj (MFMA): xz_bf = xnorm @ in_proj_w   [8192 x 3072, K=768]
    mfma_gemm_k<3><<<dim3(3072 / 128, NROWS / 128), 256, 0, stream>>>(
        xnorm_bf, w1t, xz_bf, NROWS, 2 * D_INNER, D_MODEL, nullptr);

    // 3. depthwise conv + SiLU -> xi (fp32)
    conv_silu_k<<<(NROWS * D_INNER) / 256, 256, 0, stream>>>(xz_bf, convw, convb, xi);

    // 4. x_proj: xdbl = xi @ x_proj_w  [8192 x 80, K=1536]
    gemm_k<0><<<dim3(2, NROWS / 64), 256, 0, stream>>>(xi, xprojw, xdbl, NROWS, 80, D_INNER,
                                                       D_INNER, 80, 80, nullptr);

    // 5. dt_proj + softplus
    gemm_k<1><<<dim3(D_INNER / 64, NROWS / 64), 256, 0, stream>>>(xdbl, dtpw, dt, NROWS, D_INNER,
                                                                  DT_RANK, 80, D_INNER, D_INNER, dtbias);

    // 6. chunked selective scan
    scanA_k<<<(NB * NCHUNK * D_INNER) / 16, 256, 0, stream>>>(dt, xi, xdbl, Alog, hend, dtsum);
    scanB_k<<<(NB * D_INNER * 16) / 256, 256, 0, stream>>>(hend, dtsum, Alog, carry);
    scanC_k<<<(NB * NCHUNK * D_INNER) / 16, 256, 0, stream>>>(dt, xi, xdbl, xz_bf, Alog, Dp,
                                                              carry, y_bf);

    // 7. out_proj (MFMA) + residual: out = y @ out_proj_w + seq
    mfma_gemm_k<2><<<dim3(D_MODEL / 128, NROWS / 128), 256, 0, stream>>>(
        y_bf, w4t, out, NROWS, D_MODEL, D_INNER, seq);
}

// Round 6
// 648.592 us; speedup vs baseline: 4.3236x; 1.5688x over previous
//
#include <hip/hip_runtime.h>
#include <hip/hip_bf16.h>
#include <cstdint>
#include <cstddef>

#define D_MODEL 768
#define D_STATE 16
#define D_CONV  4
#define D_INNER 1536
#define DT_RANK 48
#define NB      4
#define NL      2048
#define NROWS   (NB * NL)   // 8192
#define EPS     1e-5f
#define NCHUNK  32
#define CHUNK   (NL / NCHUNK)   // 64

typedef __bf16 bf16x8 __attribute__((ext_vector_type(8)));
typedef float  f32x4  __attribute__((ext_vector_type(4)));
typedef __hip_bfloat16 bf16_t;

__device__ __forceinline__ float siluf(float x) { return x / (1.f + __expf(-x)); }
__device__ __forceinline__ float softplusf(float x) {
    return x > 20.f ? x : log1pf(__expf(x));
}
__device__ __forceinline__ void gload16(const void* g, void* l) {
    __builtin_amdgcn_global_load_lds((const __attribute__((address_space(1))) unsigned int*)g,
                                     (__attribute__((address_space(3))) unsigned int*)l, 16, 0, 0);
}

// ---------------------------------------------------------------- RMSNorm ---
__global__ __launch_bounds__(256) void rmsnorm_k(const float* __restrict__ seq,
                                                 const float* __restrict__ w,
                                                 bf16_t* __restrict__ out) {
    int row = blockIdx.x;
    const float* x = seq + (size_t)row * D_MODEL;
    bf16_t* o = out + (size_t)row * D_MODEL;
    int t = threadIdx.x;
    float v0 = x[t], v1 = x[t + 256], v2 = x[t + 512];
    float ss = v0 * v0 + v1 * v1 + v2 * v2;
#pragma unroll
    for (int off = 32; off; off >>= 1) ss += __shfl_down(ss, off, 64);
    __shared__ float parts[4];
    if ((t & 63) == 0) parts[t >> 6] = ss;
    __syncthreads();
    float tot = parts[0] + parts[1] + parts[2] + parts[3];
    float rs = rsqrtf(tot / (float)D_MODEL + EPS);
    o[t]       = __float2bfloat16(v0 * rs * w[t]);
    o[t + 256] = __float2bfloat16(v1 * rs * w[t + 256]);
    o[t + 512] = __float2bfloat16(v2 * rs * w[t + 512]);
}

// --------------------------------------------- weight transpose + convert ---
__global__ __launch_bounds__(256) void transpose_bf16_k(const float* __restrict__ w,
                                                        bf16_t* __restrict__ wt,
                                                        int K, int N) {
    __shared__ float t[32][33];
    int bx = blockIdx.x * 32, by = blockIdx.y * 32;
    int tx = threadIdx.x & 31, ty = threadIdx.x >> 5;
#pragma unroll
    for (int i = 0; i < 32; i += 8)
        t[ty + i][tx] = w[(size_t)(by + ty + i) * N + bx + tx];
    __syncthreads();
#pragma unroll
    for (int i = 0; i < 32; i += 8)
        wt[(size_t)(bx + ty + i) * K + by + tx] = __float2bfloat16(t[tx][ty + i]);
}

// ------------------------------------------------------- bf16 MFMA GEMM -----
template <int EPI>
__global__ __launch_bounds__(256) void mfma_gemm_k(const bf16_t* __restrict__ A,
                                                   const bf16_t* __restrict__ Bt,
                                                   void* __restrict__ Cv,
                                                   int M, int N, int K,
                                                   const float* __restrict__ aux) {
    __shared__ bf16_t As[128][64];
    __shared__ bf16_t Bs[128][64];
    const int tid = threadIdx.x;
    const int lane = tid & 63, wid = tid >> 6;
    const int bm = blockIdx.y * 128, bn = blockIdx.x * 128;
    const int wm = wid >> 1, wn = wid & 1;
    f32x4 acc[4][4] = {};
    for (int k0 = 0; k0 < K; k0 += 64) {
#pragma unroll
        for (int i = 0; i < 4; i++) {
            int idx = tid + i * 256;
            int r = idx >> 3, c = idx & 7;
            gload16(A + (size_t)(bm + r) * K + k0 + ((c ^ (r & 7)) << 3),
                    (bf16_t*)As + idx * 8);
        }
#pragma unroll
        for (int i = 0; i < 4; i++) {
            int idx = tid + i * 256;
            int r = idx >> 3, c = idx & 7;
            gload16(Bt + (size_t)(bn + r) * K + k0 + ((c ^ (r & 7)) << 3),
                    (bf16_t*)Bs + idx * 8);
        }
        asm volatile("s_waitcnt vmcnt(0)" ::: "memory");
        __syncthreads();
#pragma unroll
        for (int ks = 0; ks < 2; ks++) {
            bf16x8 af[4], bfr[4];
#pragma unroll
            for (int i = 0; i < 4; i++) {
                int row = wm * 64 + i * 16 + (lane & 15);
                int cl = ks * 4 + (lane >> 4);
                af[i] = *(const bf16x8*)(&As[row][(cl ^ (row & 7)) << 3]);
            }
#pragma unroll
            for (int j = 0; j < 4; j++) {
                int row = wn * 64 + j * 16 + (lane & 15);
                int cl = ks * 4 + (lane >> 4);
                bfr[j] = *(const bf16x8*)(&Bs[row][(cl ^ (row & 7)) << 3]);
            }
#pragma unroll
            for (int i = 0; i < 4; i++)
#pragma unroll
                for (int j = 0; j < 4; j++)
                    acc[i][j] = __builtin_amdgcn_mfma_f32_16x16x32_bf16(
                        af[i], bfr[j], acc[i][j], 0, 0, 0);
        }
        __syncthreads();
    }
#pragma unroll
    for (int i = 0; i < 4; i++) {
#pragma unroll
        for (int j = 0; j < 4; j++) {
#pragma unroll
            for (int q = 0; q < 4; q++) {
                int row = bm + wm * 64 + i * 16 + (lane >> 4) * 4 + q;
                int col = bn + wn * 64 + j * 16 + (lane & 15);
                float v = acc[i][j][q];
                if (EPI == 2) {
                    ((float*)Cv)[(size_t)row * N + col] = v + aux[(size_t)row * N + col];
                } else {
                    ((bf16_t*)Cv)[(size_t)row * N + col] = __float2bfloat16(v);
                }
            }
        }
    }
}

// ----------------------------------------------------- fp32 tiled GEMM ------
template <int EPI>
__global__ __launch_bounds__(256) void gemm_k(const float* __restrict__ A,
                                              const float* __restrict__ B,
                                              float* __restrict__ C,
                                              int M, int N, int K,
                                              int lda, int ldb, int ldc,
                                              const float* __restrict__ aux) {
    __shared__ float As[16][64];
    __shared__ float Bs[16][64];
    const int tid = threadIdx.x;
    const int tx = tid & 15, ty = tid >> 4;
    const int bm = blockIdx.y * 64, bn = blockIdx.x * 64;
    float acc[4][4] = {};
    for (int k0 = 0; k0 < K; k0 += 16) {
#pragma unroll
        for (int i = 0; i < 4; i++) {
            int idx = tid + i * 256;
            int r = idx >> 4, kk = idx & 15;
            int gk = k0 + kk;
            As[kk][r ^ (kk << 2)] = (gk < K) ? A[(size_t)(bm + r) * lda + gk] : 0.f;
        }
#pragma unroll
        for (int i = 0; i < 4; i++) {
            int idx = tid + i * 256;
            int kk = idx >> 6, c = idx & 63;
            int gk = k0 + kk, gc = bn + c;
            Bs[kk][c] = (gk < K && gc < N) ? B[(size_t)gk * ldb + gc] : 0.f;
        }
        __syncthreads();
#pragma unroll
        for (int kk = 0; kk < 16; kk++) {
            float4 bv = *reinterpret_cast<const float4*>(&Bs[kk][tx * 4]);
            float b[4] = {bv.x, bv.y, bv.z, bv.w};
            float a[4];
#pragma unroll
            for (int i = 0; i < 4; i++) a[i] = As[kk][(ty * 4 + i) ^ (kk << 2)];
#pragma unroll
            for (int i = 0; i < 4; i++)
#pragma unroll
                for (int j = 0; j < 4; j++) acc[i][j] += a[i] * b[j];
        }
        __syncthreads();
    }
#pragma unroll
    for (int i = 0; i < 4; i++) {
        int row = bm + ty * 4 + i;
#pragma unroll
        for (int j = 0; j < 4; j++) {
            int col = bn + tx * 4 + j;
            if (col < N) {
                float v = acc[i][j];
                if (EPI == 1) v = softplusf(v + aux[col]);
                C[(size_t)row * ldc + col] = v;
            }
        }
    }
}

// -------------------------------------------------- depthwise conv + SiLU ---
__global__ __launch_bounds__(256) void conv_silu_k(const bf16_t* __restrict__ xz,
                                                   const float* __restrict__ cw,
                                                   const float* __restrict__ cb,
                                                   float* __restrict__ xi) {
    int idx = blockIdx.x * 256 + threadIdx.x;
    int d = idx % D_INNER;
    int row = idx / D_INNER;   // b*NL + l
    int l = row % NL;
    float w0 = cw[d * 4 + 0], w1 = cw[d * 4 + 1];
    float w2 = cw[d * 4 + 2], w3 = cw[d * 4 + 3];
    const bf16_t* base = xz + (size_t)row * (2 * D_INNER) + d;
    float acc = cb[d] + w3 * __bfloat162float(base[0]);
    if (l >= 1) acc += w2 * __bfloat162float(base[-(ptrdiff_t)(2 * D_INNER)]);
    if (l >= 2) acc += w1 * __bfloat162float(base[-(ptrdiff_t)(4 * D_INNER)]);
    if (l >= 3) acc += w0 * __bfloat162float(base[-(ptrdiff_t)(6 * D_INNER)]);
    xi[idx] = siluf(acc);
}

// --------------------------------------------------- scan phase A: carries --
// ONE LANE per (b, chunk, d): all 16 states in registers; B rows staged in LDS.
__global__ __launch_bounds__(256) void scanA_k(const float* __restrict__ dtb,
                                               const float* __restrict__ xi,
                                               const float* __restrict__ xdbl,
                                               const float* __restrict__ A_log,
                                               float* __restrict__ hend,
                                               float* __restrict__ dtsum) {
    __shared__ float Bsh[CHUNK][16];
    const int d = blockIdx.x * 256 + threadIdx.x;
    const int c = blockIdx.y, b = blockIdx.z;
    const size_t rowbase = (size_t)b * NL + (size_t)c * CHUNK;
    // stage B rows: CHUNK*4 float4s, coalesced
    const float* bsrc = xdbl + rowbase * 80 + DT_RANK;
    {
        int i = threadIdx.x;           // CHUNK*4 == 256
        int row = i >> 2, c4 = i & 3;
        *(float4*)&Bsh[row][c4 * 4] = *(const float4*)&bsrc[(size_t)row * 80 + c4 * 4];
    }
    __syncthreads();
    float Av[16];
#pragma unroll
    for (int q = 0; q < 4; q++) {
        float4 a4 = *(const float4*)&A_log[(size_t)d * 16 + q * 4];
        Av[q * 4 + 0] = -__expf(a4.x);
        Av[q * 4 + 1] = -__expf(a4.y);
        Av[q * 4 + 2] = -__expf(a4.z);
        Av[q * 4 + 3] = -__expf(a4.w);
    }
    float h[16];
#pragma unroll
    for (int s = 0; s < 16; s++) h[s] = 0.f;
    float dts = 0.f;
    const float* dtp = dtb + rowbase * D_INNER + d;
    const float* xp  = xi  + rowbase * D_INNER + d;
    float dt_n = dtp[0], x_n = xp[0];
    for (int l = 0; l < CHUNK; l++) {
        float dt_c = dt_n, x_c = x_n;
        if (l + 1 < CHUNK) {
            dt_n = dtp[(size_t)(l + 1) * D_INNER];
            x_n  = xp[(size_t)(l + 1) * D_INNER];
        }
        float4 b0 = *(const float4*)&Bsh[l][0];
        float4 b1 = *(const float4*)&Bsh[l][4];
        float4 b2 = *(const float4*)&Bsh[l][8];
        float4 b3 = *(const float4*)&Bsh[l][12];
        float Bv[16] = {b0.x, b0.y, b0.z, b0.w, b1.x, b1.y, b1.z, b1.w,
                        b2.x, b2.y, b2.z, b2.w, b3.x, b3.y, b3.z, b3.w};
        float dtx = dt_c * x_c;
#pragma unroll
        for (int s = 0; s < 16; s++)
            h[s] = h[s] * __expf(dt_c * Av[s]) + dtx * Bv[s];
        dts += dt_c;
    }
    size_t gi = ((size_t)(b * NCHUNK + c) * D_INNER + d) * 16;
#pragma unroll
    for (int q = 0; q < 4; q++)
        *(float4*)&hend[gi + q * 4] =
            make_float4(h[q * 4], h[q * 4 + 1], h[q * 4 + 2], h[q * 4 + 3]);
    dtsum[gi >> 4] = dts;
}

// --------------------------------------------- scan phase B: combine carries -
__global__ __launch_bounds__(256) void scanB_k(const float* __restrict__ hend,
                                               const float* __restrict__ dtsum,
                                               const float* __restrict__ A_log,
                                               float* __restrict__ carry) {
    int t = blockIdx.x * 256 + threadIdx.x;   // (b*D_INNER+d)*16+s
    int s = t & 15;
    int bd = t >> 4;
    int b = bd / D_INNER, d = bd % D_INNER;
    float Av = -__expf(A_log[d * D_STATE + s]);
    float h = 0.f;
    for (int c = 0; c < NCHUNK; c++) {
        size_t gi = (size_t)(b * NCHUNK + c) * D_INNER + d;
        carry[gi * 16 + s] = h;
        h = h * __expf(Av * dtsum[gi]) + hend[gi * 16 + s];
    }
}

// ------------------------------- scan phase C: full scan + gating, y -> bf16 -
// ONE LANE per (b, chunk, d); B+C rows staged in LDS.
__global__ __launch_bounds__(256) void scanC_k(const float* __restrict__ dtb,
                                               const float* __restrict__ xi,
                                               const float* __restrict__ xdbl,
                                               const bf16_t* __restrict__ xz,
                                               const float* __restrict__ A_log,
                                               const float* __restrict__ Dp,
                                               const float* __restrict__ carry,
                                               bf16_t* __restrict__ yb) {
    __shared__ float BC[CHUNK][32];
    const int d = blockIdx.x * 256 + threadIdx.x;
    const int c = blockIdx.y, b = blockIdx.z;
    const size_t rowbase = (size_t)b * NL + (size_t)c * CHUNK;
    const float* src = xdbl + rowbase * 80 + DT_RANK;
#pragma unroll
    for (int ii = 0; ii < 2; ii++) {      // CHUNK*8 == 512 float4s
        int i = threadIdx.x + ii * 256;
        int row = i >> 3, c4 = i & 7;
        *(float4*)&BC[row][c4 * 4] = *(const float4*)&src[(size_t)row * 80 + c4 * 4];
    }
    __syncthreads();
    float Av[16];
#pragma unroll
    for (int q = 0; q < 4; q++) {
        float4 a4 = *(const float4*)&A_log[(size_t)d * 16 + q * 4];
        Av[q * 4 + 0] = -__expf(a4.x);
        Av[q * 4 + 1] = -__expf(a4.y);
        Av[q * 4 + 2] = -__expf(a4.z);
        Av[q * 4 + 3] = -__expf(a4.w);
    }
    float Dd = Dp[d];
    float h[16];
    size_t gi = ((size_t)(b * NCHUNK + c) * D_INNER + d) * 16;
#pragma unroll
    for (int q = 0; q < 4; q++) {
        float4 c4v = *(const float4*)&carry[gi + q * 4];
        h[q * 4 + 0] = c4v.x; h[q * 4 + 1] = c4v.y;
        h[q * 4 + 2] = c4v.z; h[q * 4 + 3] = c4v.w;
    }
    const float* dtp = dtb + rowbase * D_INNER + d;
    const float* xp  = xi  + rowbase * D_INNER + d;
    const bf16_t* zp = xz + rowbase * (2 * D_INNER) + D_INNER + d;
    bf16_t* yp = yb + rowbase * D_INNER + d;
    float dt_n = dtp[0], x_n = xp[0];
    bf16_t z_n = zp[0];
    for (int l = 0; l < CHUNK; l++) {
        float dt_c = dt_n, x_c = x_n;
        float z_c = __bfloat162float(z_n);
        if (l + 1 < CHUNK) {
            dt_n = dtp[(size_t)(l + 1) * D_INNER];
            x_n  = xp[(size_t)(l + 1) * D_INNER];
            z_n  = zp[(size_t)(l + 1) * (2 * D_INNER)];
        }
        float4 b0 = *(const float4*)&BC[l][0];
        float4 b1 = *(const float4*)&BC[l][4];
        float4 b2 = *(const float4*)&BC[l][8];
        float4 b3 = *(const float4*)&BC[l][12];
        float4 c0 = *(const float4*)&BC[l][16];
        float4 c1 = *(const float4*)&BC[l][20];
        float4 c2 = *(const float4*)&BC[l][24];
        float4 c3 = *(const float4*)&BC[l][28];
        float Bv[16] = {b0.x, b0.y, b0.z, b0.w, b1.x, b1.y, b1.z, b1.w,
                        b2.x, b2.y, b2.z, b2.w, b3.x, b3.y, b3.z, b3.w};
        float Cv[16] = {c0.x, c0.y, c0.z, c0.w, c1.x, c1.y, c1.z, c1.w,
                        c2.x, c2.y, c2.z, c2.w, c3.x, c3.y, c3.z, c3.w};
        float dtx = dt_c * x_c;
        float p = Dd * x_c;
#pragma unroll
        for (int s = 0; s < 16; s++) {
            h[s] = h[s] * __expf(dt_c * Av[s]) + dtx * Bv[s];
            p += h[s] * Cv[s];
        }
        yp[(size_t)l * D_INNER] = __float2bfloat16(p * siluf(z_c));
    }
}

// ----------------------------------------------------------------- launch ---
extern "C" void kernel_launch(void* const* d_in, const int* in_sizes, int n_in,
                              void* d_out, int out_size, void* d_ws, size_t ws_size,
                              hipStream_t stream) {
    const float* seq    = (const float*)d_in[0];
    const float* normw  = (const float*)d_in[1];
    const float* inpw   = (const float*)d_in[2];
    const float* convw  = (const float*)d_in[3];
    const float* convb  = (const float*)d_in[4];
    const float* xprojw = (const float*)d_in[5];
    const float* dtpw   = (const float*)d_in[6];
    const float* dtbias = (const float*)d_in[7];
    const float* Alog   = (const float*)d_in[8];
    const float* Dp     = (const float*)d_in[9];
    const float* outpw  = (const float*)d_in[10];
    float* out = (float*)d_out;

    float* ws = (float*)d_ws;
    float* xi    = ws;                       // 8192*1536  = 12582912 f
    float* dt    = xi + 12582912;            // 12582912 f
    float* xdbl  = dt + 12582912;            // 8192*80    = 655360 f
    float* hend  = xdbl + 655360;            // 4*32*1536*16 = 3145728 f
    float* carry = hend + 3145728;           // 3145728 f
    float* dtsum = carry + 3145728;          // 4*32*1536  = 196608 f
    bf16_t* xz_bf    = (bf16_t*)(dtsum + 196608);  // 8192*3072 = 25165824 bf16
    bf16_t* xnorm_bf = xz_bf + 25165824;           // 8192*768  = 6291456
    bf16_t* y_bf     = xnorm_bf + 6291456;         // 8192*1536 = 12582912
    bf16_t* w1t      = y_bf + 12582912;            // 3072*768  = 2359296
    bf16_t* w4t      = w1t + 2359296;              // 768*1536  = 1179648

    // 1. RMSNorm (bf16 out)
    rmsnorm_k<<<NROWS, 256, 0, stream>>>(seq, normw, xnorm_bf);

    // 1b. weight transposes -> bf16 [N][K]
    transpose_bf16_k<<<dim3(3072 / 32, 768 / 32), 256, 0, stream>>>(inpw, w1t, D_MODEL, 2 * D_INNER);
    transpose_bf16_k<<<dim3(768 / 32, 1536 / 32), 256, 0, stream>>>(outpw, w4t, D_INNER, D_MODEL);

    // 2. in_proj (MFMA): xz_bf = xnorm @ in_proj_w   [8192 x 3072, K=768]
    mfma_gemm_k<3><<<dim3(3072 / 128, NROWS / 128), 256, 0, stream>>>(
        xnorm_bf, w1t, xz_bf, NROWS, 2 * D_INNER, D_MODEL, nullptr);

    // 3. depthwise conv + SiLU -> xi (fp32)
    conv_silu_k<<<(NROWS * D_INNER) / 256, 256, 0, stream>>>(xz_bf, convw, convb, xi);

    // 4. x_proj: xdbl = xi @ x_proj_w  [8192 x 80, K=1536]
    gemm_k<0><<<dim3(2, NROWS / 64), 256, 0, stream>>>(xi, xprojw, xdbl, NROWS, 80, D_INNER,
                                                       D_INNER, 80, 80, nullptr);

    // 5. dt_proj + softplus
    gemm_k<1><<<dim3(D_INNER / 64, NROWS / 64), 256, 0, stream>>>(xdbl, dtpw, dt, NROWS, D_INNER,
                                                                  DT_RANK, 80, D_INNER, D_INNER, dtbias);

    // 6. chunked selective scan (lane-per-channel, h[16] in registers)
    scanA_k<<<dim3(D_INNER / 256, NCHUNK, NB), 256, 0, stream>>>(dt, xi, xdbl, Alog, hend, dtsum);
    scanB_k<<<(NB * D_INNER * 16) / 256, 256, 0, stream>>>(hend, dtsum, Alog, carry);
    scanC_k<<<dim3(D_INNER / 256, NCHUNK, NB), 256, 0, stream>>>(dt, xi, xdbl, xz_bf, Alog, Dp,
                                                                 carry, y_bf);

    // 7. out_proj (MFMA) + residual: out = y @ out_proj_w + seq
    mfma_gemm_k<2><<<dim3(D_MODEL / 128, NROWS / 128), 256, 0, stream>>>(
        y_bf, w4t, out, NROWS, D_MODEL, D_INNER, seq);
}

// Round 9
// 440.484 us; speedup vs baseline: 6.3662x; 1.4725x over previous
//
#include <hip/hip_runtime.h>
#include <hip/hip_bf16.h>
#include <cstdint>
#include <cstddef>

#define D_MODEL 768
#define D_STATE 16
#define D_CONV  4
#define D_INNER 1536
#define DT_RANK 48
#define NB      4
#define NL      2048
#define NROWS   (NB * NL)   // 8192
#define EPS     1e-5f
#define NCHUNK  32
#define CHUNK   (NL / NCHUNK)   // 64
#define XP_SPLIT 8
#define XP_KR   (D_INNER / XP_SPLIT)   // 192

typedef __bf16 bf16x8 __attribute__((ext_vector_type(8)));
typedef float  f32x4  __attribute__((ext_vector_type(4)));
typedef __hip_bfloat16 bf16_t;

__device__ __forceinline__ float siluf(float x) { return x / (1.f + __expf(-x)); }
__device__ __forceinline__ float softplusf(float x) {
    return x > 20.f ? x : log1pf(__expf(x));
}
__device__ __forceinline__ void gload16(const void* g, void* l) {
    __builtin_amdgcn_global_load_lds((const __attribute__((address_space(1))) unsigned int*)g,
                                     (__attribute__((address_space(3))) unsigned int*)l, 16, 0, 0);
}

// ---------------------------------------------------------------- RMSNorm ---
__global__ __launch_bounds__(256) void rmsnorm_k(const float* __restrict__ seq,
                                                 const float* __restrict__ w,
                                                 bf16_t* __restrict__ out) {
    int row = blockIdx.x;
    const float* x = seq + (size_t)row * D_MODEL;
    bf16_t* o = out + (size_t)row * D_MODEL;
    int t = threadIdx.x;
    float v0 = x[t], v1 = x[t + 256], v2 = x[t + 512];
    float ss = v0 * v0 + v1 * v1 + v2 * v2;
#pragma unroll
    for (int off = 32; off; off >>= 1) ss += __shfl_down(ss, off, 64);
    __shared__ float parts[4];
    if ((t & 63) == 0) parts[t >> 6] = ss;
    __syncthreads();
    float tot = parts[0] + parts[1] + parts[2] + parts[3];
    float rs = rsqrtf(tot / (float)D_MODEL + EPS);
    o[t]       = __float2bfloat16(v0 * rs * w[t]);
    o[t + 256] = __float2bfloat16(v1 * rs * w[t + 256]);
    o[t + 512] = __float2bfloat16(v2 * rs * w[t + 512]);
}

// --------------------------------------------- weight transpose + convert ---
// w [K][N] fp32 -> wt [N][K] bf16 (N bounds-guarded; K must be %32)
__global__ __launch_bounds__(256) void transpose_bf16_k(const float* __restrict__ w,
                                                        bf16_t* __restrict__ wt,
                                                        int K, int N) {
    __shared__ float t[32][33];
    int bx = blockIdx.x * 32, by = blockIdx.y * 32;
    int tx = threadIdx.x & 31, ty = threadIdx.x >> 5;
#pragma unroll
    for (int i = 0; i < 32; i += 8)
        if (bx + tx < N)
            t[ty + i][tx] = w[(size_t)(by + ty + i) * N + bx + tx];
    __syncthreads();
#pragma unroll
    for (int i = 0; i < 32; i += 8)
        if (bx + ty + i < N)
            wt[(size_t)(bx + ty + i) * K + by + tx] = __float2bfloat16(t[tx][ty + i]);
}

// ------------------------------------------------------- bf16 MFMA GEMM -----
template <int EPI>
__global__ __launch_bounds__(256) void mfma_gemm_k(const bf16_t* __restrict__ A,
                                                   const bf16_t* __restrict__ Bt,
                                                   void* __restrict__ Cv,
                                                   int M, int N, int K,
                                                   const float* __restrict__ aux) {
    __shared__ bf16_t As[128][64];
    __shared__ bf16_t Bs[128][64];
    const int tid = threadIdx.x;
    const int lane = tid & 63, wid = tid >> 6;
    const int bm = blockIdx.y * 128, bn = blockIdx.x * 128;
    const int wm = wid >> 1, wn = wid & 1;
    f32x4 acc[4][4] = {};
    for (int k0 = 0; k0 < K; k0 += 64) {
#pragma unroll
        for (int i = 0; i < 4; i++) {
            int idx = tid + i * 256;
            int r = idx >> 3, c = idx & 7;
            gload16(A + (size_t)(bm + r) * K + k0 + ((c ^ (r & 7)) << 3),
                    (bf16_t*)As + idx * 8);
        }
#pragma unroll
        for (int i = 0; i < 4; i++) {
            int idx = tid + i * 256;
            int r = idx >> 3, c = idx & 7;
            gload16(Bt + (size_t)(bn + r) * K + k0 + ((c ^ (r & 7)) << 3),
                    (bf16_t*)Bs + idx * 8);
        }
        asm volatile("s_waitcnt vmcnt(0)" ::: "memory");
        __syncthreads();
#pragma unroll
        for (int ks = 0; ks < 2; ks++) {
            bf16x8 af[4], bfr[4];
#pragma unroll
            for (int i = 0; i < 4; i++) {
                int row = wm * 64 + i * 16 + (lane & 15);
                int cl = ks * 4 + (lane >> 4);
                af[i] = *(const bf16x8*)(&As[row][(cl ^ (row & 7)) << 3]);
            }
#pragma unroll
            for (int j = 0; j < 4; j++) {
                int row = wn * 64 + j * 16 + (lane & 15);
                int cl = ks * 4 + (lane >> 4);
                bfr[j] = *(const bf16x8*)(&Bs[row][(cl ^ (row & 7)) << 3]);
            }
#pragma unroll
            for (int i = 0; i < 4; i++)
#pragma unroll
                for (int j = 0; j < 4; j++)
                    acc[i][j] = __builtin_amdgcn_mfma_f32_16x16x32_bf16(
                        af[i], bfr[j], acc[i][j], 0, 0, 0);
        }
        __syncthreads();
    }
#pragma unroll
    for (int i = 0; i < 4; i++) {
#pragma unroll
        for (int j = 0; j < 4; j++) {
#pragma unroll
            for (int q = 0; q < 4; q++) {
                int row = bm + wm * 64 + i * 16 + (lane >> 4) * 4 + q;
                int col = bn + wn * 64 + j * 16 + (lane & 15);
                float v = acc[i][j][q];
                if (EPI == 2) {
                    ((float*)Cv)[(size_t)row * N + col] = v + aux[(size_t)row * N + col];
                } else {
                    ((bf16_t*)Cv)[(size_t)row * N + col] = __float2bfloat16(v);
                }
            }
        }
    }
}

// --------------------------------------- x_proj: split-K skinny MFMA GEMM ---
// C[8192][80] += A[8192][1536]bf16 * Bt[80][1536]^T, K split 8 ways, atomicAdd.
__global__ __launch_bounds__(256) void xproj_k(const bf16_t* __restrict__ A,
                                               const bf16_t* __restrict__ Bt,
                                               float* __restrict__ C) {
    __shared__ bf16_t As[64][64];
    __shared__ bf16_t Bs[80][64];
    const int tid = threadIdx.x;
    const int lane = tid & 63, wid = tid >> 6;   // 4 waves
    const int bm = blockIdx.x * 64;
    const int k0base = blockIdx.y * XP_KR;
    f32x4 acc[5] = {};
    for (int kt = 0; kt < XP_KR; kt += 64) {
        int k0 = k0base + kt;
#pragma unroll
        for (int i = 0; i < 2; i++) {            // A: 512 chunks
            int idx = tid + i * 256;
            int r = idx >> 3, c = idx & 7;
            gload16(A + (size_t)(bm + r) * D_INNER + k0 + ((c ^ (r & 7)) << 3),
                    (bf16_t*)As + idx * 8);
        }
#pragma unroll
        for (int i = 0; i < 3; i++) {            // B: 640 chunks (wave-uniform guard)
            int idx = tid + i * 256;
            if (idx < 640) {
                int r = idx >> 3, c = idx & 7;
                gload16(Bt + (size_t)r * D_INNER + k0 + ((c ^ (r & 7)) << 3),
                        (bf16_t*)Bs + idx * 8);
            }
        }
        asm volatile("s_waitcnt vmcnt(0)" ::: "memory");
        __syncthreads();
#pragma unroll
        for (int ks = 0; ks < 2; ks++) {
            int arow = wid * 16 + (lane & 15);
            int cl = ks * 4 + (lane >> 4);
            bf16x8 af = *(const bf16x8*)(&As[arow][(cl ^ (arow & 7)) << 3]);
#pragma unroll
            for (int j = 0; j < 5; j++) {
                int brow = j * 16 + (lane & 15);
                bf16x8 bf_ = *(const bf16x8*)(&Bs[brow][(cl ^ (brow & 7)) << 3]);
                acc[j] = __builtin_amdgcn_mfma_f32_16x16x32_bf16(af, bf_, acc[j], 0, 0, 0);
            }
        }
        __syncthreads();
    }
#pragma unroll
    for (int j = 0; j < 5; j++)
#pragma unroll
        for (int q = 0; q < 4; q++) {
            int row = bm + wid * 16 + (lane >> 4) * 4 + q;
            int col = j * 16 + (lane & 15);
            atomicAdd(&C[(size_t)row * 80 + col], acc[j][q]);
        }
}

// ----------------------------------------------------- fp32 tiled GEMM ------
template <int EPI>
__global__ __launch_bounds__(256) void gemm_k(const float* __restrict__ A,
                                              const float* __restrict__ B,
                                              float* __restrict__ C,
                                              int M, int N, int K,
                                              int lda, int ldb, int ldc,
                                              const float* __restrict__ aux) {
    __shared__ float As[16][64];
    __shared__ float Bs[16][64];
    const int tid = threadIdx.x;
    const int tx = tid & 15, ty = tid >> 4;
    const int bm = blockIdx.y * 64, bn = blockIdx.x * 64;
    float acc[4][4] = {};
    for (int k0 = 0; k0 < K; k0 += 16) {
#pragma unroll
        for (int i = 0; i < 4; i++) {
            int idx = tid + i * 256;
            int r = idx >> 4, kk = idx & 15;
            int gk = k0 + kk;
            As[kk][r ^ (kk << 2)] = (gk < K) ? A[(size_t)(bm + r) * lda + gk] : 0.f;
        }
#pragma unroll
        for (int i = 0; i < 4; i++) {
            int idx = tid + i * 256;
            int kk = idx >> 6, c = idx & 63;
            int gk = k0 + kk, gc = bn + c;
            Bs[kk][c] = (gk < K && gc < N) ? B[(size_t)gk * ldb + gc] : 0.f;
        }
        __syncthreads();
#pragma unroll
        for (int kk = 0; kk < 16; kk++) {
            float4 bv = *reinterpret_cast<const float4*>(&Bs[kk][tx * 4]);
            float b[4] = {bv.x, bv.y, bv.z, bv.w};
            float a[4];
#pragma unroll
            for (int i = 0; i < 4; i++) a[i] = As[kk][(ty * 4 + i) ^ (kk << 2)];
#pragma unroll
            for (int i = 0; i < 4; i++)
#pragma unroll
                for (int j = 0; j < 4; j++) acc[i][j] += a[i] * b[j];
        }
        __syncthreads();
    }
#pragma unroll
    for (int i = 0; i < 4; i++) {
        int row = bm + ty * 4 + i;
#pragma unroll
        for (int j = 0; j < 4; j++) {
            int col = bn + tx * 4 + j;
            if (col < N) {
                float v = acc[i][j];
                if (EPI == 1) v = softplusf(v + aux[col]);
                C[(size_t)row * ldc + col] = v;
            }
        }
    }
}

// -------------------------------------------------- depthwise conv + SiLU ---
// output bf16 now (feeds x_proj MFMA and the scan)
__global__ __launch_bounds__(256) void conv_silu_k(const bf16_t* __restrict__ xz,
                                                   const float* __restrict__ cw,
                                                   const float* __restrict__ cb,
                                                   bf16_t* __restrict__ xi) {
    int idx = blockIdx.x * 256 + threadIdx.x;
    int d = idx % D_INNER;
    int row = idx / D_INNER;   // b*NL + l
    int l = row % NL;
    float w0 = cw[d * 4 + 0], w1 = cw[d * 4 + 1];
    float w2 = cw[d * 4 + 2], w3 = cw[d * 4 + 3];
    const bf16_t* base = xz + (size_t)row * (2 * D_INNER) + d;
    float acc = cb[d] + w3 * __bfloat162float(base[0]);
    if (l >= 1) acc += w2 * __bfloat162float(base[-(ptrdiff_t)(2 * D_INNER)]);
    if (l >= 2) acc += w1 * __bfloat162float(base[-(ptrdiff_t)(4 * D_INNER)]);
    if (l >= 3) acc += w0 * __bfloat162float(base[-(ptrdiff_t)(6 * D_INNER)]);
    xi[idx] = __float2bfloat16(siluf(acc));
}

// --------------------------------------------------- scan phase A: carries --
__global__ __launch_bounds__(256) void scanA_k(const float* __restrict__ dtb,
                                               const bf16_t* __restrict__ xi,
                                               const float* __restrict__ xdbl,
                                               const float* __restrict__ A_log,
                                               float* __restrict__ hend,
                                               float* __restrict__ dtsum) {
    __shared__ float Bsh[CHUNK][16];
    const int d = blockIdx.x * 256 + threadIdx.x;
    const int c = blockIdx.y, b = blockIdx.z;
    const size_t rowbase = (size_t)b * NL + (size_t)c * CHUNK;
    const float* bsrc = xdbl + rowbase * 80 + DT_RANK;
    {
        int i = threadIdx.x;           // CHUNK*4 == 256
        int row = i >> 2, c4 = i & 3;
        *(float4*)&Bsh[row][c4 * 4] = *(const float4*)&bsrc[(size_t)row * 80 + c4 * 4];
    }
    __syncthreads();
    float Av[16];
#pragma unroll
    for (int q = 0; q < 4; q++) {
        float4 a4 = *(const float4*)&A_log[(size_t)d * 16 + q * 4];
        Av[q * 4 + 0] = -__expf(a4.x);
        Av[q * 4 + 1] = -__expf(a4.y);
        Av[q * 4 + 2] = -__expf(a4.z);
        Av[q * 4 + 3] = -__expf(a4.w);
    }
    float h[16];
#pragma unroll
    for (int s = 0; s < 16; s++) h[s] = 0.f;
    float dts = 0.f;
    const float* dtp = dtb + rowbase * D_INNER + d;
    const bf16_t* xp = xi + rowbase * D_INNER + d;
    float dt_n = dtp[0];
    bf16_t x_n = xp[0];
    for (int l = 0; l < CHUNK; l++) {
        float dt_c = dt_n, x_c = __bfloat162float(x_n);
        if (l + 1 < CHUNK) {
            dt_n = dtp[(size_t)(l + 1) * D_INNER];
            x_n  = xp[(size_t)(l + 1) * D_INNER];
        }
        float4 b0 = *(const float4*)&Bsh[l][0];
        float4 b1 = *(const float4*)&Bsh[l][4];
        float4 b2 = *(const float4*)&Bsh[l][8];
        float4 b3 = *(const float4*)&Bsh[l][12];
        float Bv[16] = {b0.x, b0.y, b0.z, b0.w, b1.x, b1.y, b1.z, b1.w,
                        b2.x, b2.y, b2.z, b2.w, b3.x, b3.y, b3.z, b3.w};
        float dtx = dt_c * x_c;
#pragma unroll
        for (int s = 0; s < 16; s++)
            h[s] = h[s] * __expf(dt_c * Av[s]) + dtx * Bv[s];
        dts += dt_c;
    }
    size_t gi = ((size_t)(b * NCHUNK + c) * D_INNER + d) * 16;
#pragma unroll
    for (int q = 0; q < 4; q++)
        *(float4*)&hend[gi + q * 4] =
            make_float4(h[q * 4], h[q * 4 + 1], h[q * 4 + 2], h[q * 4 + 3]);
    dtsum[gi >> 4] = dts;
}

// --------------------------------------------- scan phase B: combine carries -
__global__ __launch_bounds__(256) void scanB_k(const float* __restrict__ hend,
                                               const float* __restrict__ dtsum,
                                               const float* __restrict__ A_log,
                                               float* __restrict__ carry) {
    int t = blockIdx.x * 256 + threadIdx.x;   // (b*D_INNER+d)*16+s
    int s = t & 15;
    int bd = t >> 4;
    int b = bd / D_INNER, d = bd % D_INNER;
    float Av = -__expf(A_log[d * D_STATE + s]);
    float h = 0.f;
    for (int c = 0; c < NCHUNK; c++) {
        size_t gi = (size_t)(b * NCHUNK + c) * D_INNER + d;
        carry[gi * 16 + s] = h;
        h = h * __expf(Av * dtsum[gi]) + hend[gi * 16 + s];
    }
}

// ------------------------------- scan phase C: full scan + gating, y -> bf16 -
__global__ __launch_bounds__(256) void scanC_k(const float* __restrict__ dtb,
                                               const bf16_t* __restrict__ xi,
                                               const float* __restrict__ xdbl,
                                               const bf16_t* __restrict__ xz,
                                               const float* __restrict__ A_log,
                                               const float* __restrict__ Dp,
                                               const float* __restrict__ carry,
                                               bf16_t* __restrict__ yb) {
    __shared__ float BC[CHUNK][32];
    const int d = blockIdx.x * 256 + threadIdx.x;
    const int c = blockIdx.y, b = blockIdx.z;
    const size_t rowbase = (size_t)b * NL + (size_t)c * CHUNK;
    const float* src = xdbl + rowbase * 80 + DT_RANK;
#pragma unroll
    for (int ii = 0; ii < 2; ii++) {      // CHUNK*8 == 512 float4s
        int i = threadIdx.x + ii * 256;
        int row = i >> 3, c4 = i & 7;
        *(float4*)&BC[row][c4 * 4] = *(const float4*)&src[(size_t)row * 80 + c4 * 4];
    }
    __syncthreads();
    float Av[16];
#pragma unroll
    for (int q = 0; q < 4; q++) {
        float4 a4 = *(const float4*)&A_log[(size_t)d * 16 + q * 4];
        Av[q * 4 + 0] = -__expf(a4.x);
        Av[q * 4 + 1] = -__expf(a4.y);
        Av[q * 4 + 2] = -__expf(a4.z);
        Av[q * 4 + 3] = -__expf(a4.w);
    }
    float Dd = Dp[d];
    float h[16];
    size_t gi = ((size_t)(b * NCHUNK + c) * D_INNER + d) * 16;
#pragma unroll
    for (int q = 0; q < 4; q++) {
        float4 c4v = *(const float4*)&carry[gi + q * 4];
        h[q * 4 + 0] = c4v.x; h[q * 4 + 1] = c4v.y;
        h[q * 4 + 2] = c4v.z; h[q * 4 + 3] = c4v.w;
    }
    const float* dtp = dtb + rowbase * D_INNER + d;
    const bf16_t* xp = xi + rowbase * D_INNER + d;
    const bf16_t* zp = xz + rowbase * (2 * D_INNER) + D_INNER + d;
    bf16_t* yp = yb + rowbase * D_INNER + d;
    float dt_n = dtp[0];
    bf16_t x_n = xp[0], z_n = zp[0];
    for (int l = 0; l < CHUNK; l++) {
        float dt_c = dt_n, x_c = __bfloat162float(x_n);
        float z_c = __bfloat162float(z_n);
        if (l + 1 < CHUNK) {
            dt_n = dtp[(size_t)(l + 1) * D_INNER];
            x_n  = xp[(size_t)(l + 1) * D_INNER];
            z_n  = zp[(size_t)(l + 1) * (2 * D_INNER)];
        }
        float4 b0 = *(const float4*)&BC[l][0];
        float4 b1 = *(const float4*)&BC[l][4];
        float4 b2 = *(const float4*)&BC[l][8];
        float4 b3 = *(const float4*)&BC[l][12];
        float4 c0 = *(const float4*)&BC[l][16];
        float4 c1 = *(const float4*)&BC[l][20];
        float4 c2 = *(const float4*)&BC[l][24];
        float4 c3 = *(const float4*)&BC[l][28];
        float Bv[16] = {b0.x, b0.y, b0.z, b0.w, b1.x, b1.y, b1.z, b1.w,
                        b2.x, b2.y, b2.z, b2.w, b3.x, b3.y, b3.z, b3.w};
        float Cv[16] = {c0.x, c0.y, c0.z, c0.w, c1.x, c1.y, c1.z, c1.w,
                        c2.x, c2.y, c2.z, c2.w, c3.x, c3.y, c3.z, c3.w};
        float dtx = dt_c * x_c;
        float p = Dd * x_c;
#pragma unroll
        for (int s = 0; s < 16; s++) {
            h[s] = h[s] * __expf(dt_c * Av[s]) + dtx * Bv[s];
            p += h[s] * Cv[s];
        }
        yp[(size_t)l * D_INNER] = __float2bfloat16(p * siluf(z_c));
    }
}

// ----------------------------------------------------------------- launch ---
extern "C" void kernel_launch(void* const* d_in, const int* in_sizes, int n_in,
                              void* d_out, int out_size, void* d_ws, size_t ws_size,
                              hipStream_t stream) {
    const float* seq    = (const float*)d_in[0];
    const float* normw  = (const float*)d_in[1];
    const float* inpw   = (const float*)d_in[2];
    const float* convw  = (const float*)d_in[3];
    const float* convb  = (const float*)d_in[4];
    const float* xprojw = (const float*)d_in[5];
    const float* dtpw   = (const float*)d_in[6];
    const float* dtbias = (const float*)d_in[7];
    const float* Alog   = (const float*)d_in[8];
    const float* Dp     = (const float*)d_in[9];
    const float* outpw  = (const float*)d_in[10];
    float* out = (float*)d_out;

    float* ws = (float*)d_ws;
    bf16_t* xi_bf = (bf16_t*)ws;             // 8192*1536 bf16 (in old xi slot)
    float* dt    = ws + 12582912;            // 12582912 f
    float* xdbl  = dt + 12582912;            // 8192*80    = 655360 f
    float* hend  = xdbl + 655360;            // 4*32*1536*16 = 3145728 f
    float* carry = hend + 3145728;           // 3145728 f
    float* dtsum = carry + 3145728;          // 4*32*1536  = 196608 f
    bf16_t* xz_bf    = (bf16_t*)(dtsum + 196608);  // 8192*3072 = 25165824 bf16
    bf16_t* xnorm_bf = xz_bf + 25165824;           // 8192*768  = 6291456
    bf16_t* y_bf     = xnorm_bf + 6291456;         // 8192*1536 = 12582912
    bf16_t* w1t      = y_bf + 12582912;            // 3072*768  = 2359296
    bf16_t* w4t      = w1t + 2359296;              // 768*1536  = 1179648
    bf16_t* wxt      = w4t + 1179648;              // 80*1536   = 122880

    // 1. RMSNorm (bf16 out)
    rmsnorm_k<<<NROWS, 256, 0, stream>>>(seq, normw, xnorm_bf);

    // 1b. weight transposes -> bf16 [N][K]
    transpose_bf16_k<<<dim3(3072 / 32, 768 / 32), 256, 0, stream>>>(inpw, w1t, D_MODEL, 2 * D_INNER);
    transpose_bf16_k<<<dim3(768 / 32, 1536 / 32), 256, 0, stream>>>(outpw, w4t, D_INNER, D_MODEL);
    transpose_bf16_k<<<dim3(3, 1536 / 32), 256, 0, stream>>>(xprojw, wxt, D_INNER, 80);

    // zero xdbl for the split-K atomic accumulation
    hipMemsetAsync(xdbl, 0, (size_t)NROWS * 80 * sizeof(float), stream);

    // 2. in_proj (MFMA): xz_bf = xnorm @ in_proj_w   [8192 x 3072, K=768]
    mfma_gemm_k<3><<<dim3(3072 / 128, NROWS / 128), 256, 0, stream>>>(
        xnorm_bf, w1t, xz_bf, NROWS, 2 * D_INNER, D_MODEL, nullptr);

    // 3. depthwise conv + SiLU -> xi (bf16)
    conv_silu_k<<<(NROWS * D_INNER) / 256, 256, 0, stream>>>(xz_bf, convw, convb, xi_bf);

    // 4. x_proj (split-K MFMA, atomic): xdbl = xi @ x_proj_w  [8192 x 80, K=1536]
    xproj_k<<<dim3(NROWS / 64, XP_SPLIT), 256, 0, stream>>>(xi_bf, wxt, xdbl);

    // 5. dt_proj + softplus
    gemm_k<1><<<dim3(D_INNER / 64, NROWS / 64), 256, 0, stream>>>(xdbl, dtpw, dt, NROWS, D_INNER,
                                                                  DT_RANK, 80, D_INNER, D_INNER, dtbias);

    // 6. chunked selective scan (lane-per-channel, h[16] in registers)
    scanA_k<<<dim3(D_INNER / 256, NCHUNK, NB), 256, 0, stream>>>(dt, xi_bf, xdbl, Alog, hend, dtsum);
    scanB_k<<<(NB * D_INNER * 16) / 256, 256, 0, stream>>>(hend, dtsum, Alog, carry);
    scanC_k<<<dim3(D_INNER / 256, NCHUNK, NB), 256, 0, stream>>>(dt, xi_bf, xdbl, xz_bf, Alog, Dp,
                                                                 carry, y_bf);

    // 7. out_proj (MFMA) + residual: out = y @ out_proj_w + seq
    mfma_gemm_k<2><<<dim3(D_MODEL / 128, NROWS / 128), 256, 0, stream>>>(
        y_bf, w4t, out, NROWS, D_MODEL, D_INNER, seq);
}

// Round 13
// 423.299 us; speedup vs baseline: 6.6247x; 1.0406x over previous
//
#include <hip/hip_runtime.h>
#include <hip/hip_bf16.h>
#include <cstdint>
#include <cstddef>

#define D_MODEL 768
#define D_STATE 16
#define D_CONV  4
#define D_INNER 1536
#define DT_RANK 48
#define NB      4
#define NL      2048
#define NROWS   (NB * NL)   // 8192
#define EPS     1e-5f
#define NCHUNK  32
#define CHUNK   (NL / NCHUNK)   // 64
#define XP_SPLIT 8
#define XP_KR   (D_INNER / XP_SPLIT)   // 192

typedef __bf16 bf16x8 __attribute__((ext_vector_type(8)));
typedef float  f32x4  __attribute__((ext_vector_type(4)));
typedef __hip_bfloat16 bf16_t;

__device__ __forceinline__ float siluf(float x) { return x / (1.f + __expf(-x)); }
__device__ __forceinline__ float softplusf(float x) {
    return x > 20.f ? x : log1pf(__expf(x));
}
__device__ __forceinline__ void gload16(const void* g, void* l) {
    __builtin_amdgcn_global_load_lds((const __attribute__((address_space(1))) unsigned int*)g,
                                     (__attribute__((address_space(3))) unsigned int*)l, 16, 0, 0);
}

// ---------------------------------------------------------------- RMSNorm ---
__global__ __launch_bounds__(256) void rmsnorm_k(const float* __restrict__ seq,
                                                 const float* __restrict__ w,
                                                 bf16_t* __restrict__ out) {
    int row = blockIdx.x;
    const float* x = seq + (size_t)row * D_MODEL;
    bf16_t* o = out + (size_t)row * D_MODEL;
    int t = threadIdx.x;
    float v0 = x[t], v1 = x[t + 256], v2 = x[t + 512];
    float ss = v0 * v0 + v1 * v1 + v2 * v2;
#pragma unroll
    for (int off = 32; off; off >>= 1) ss += __shfl_down(ss, off, 64);
    __shared__ float parts[4];
    if ((t & 63) == 0) parts[t >> 6] = ss;
    __syncthreads();
    float tot = parts[0] + parts[1] + parts[2] + parts[3];
    float rs = rsqrtf(tot / (float)D_MODEL + EPS);
    o[t]       = __float2bfloat16(v0 * rs * w[t]);
    o[t + 256] = __float2bfloat16(v1 * rs * w[t + 256]);
    o[t + 512] = __float2bfloat16(v2 * rs * w[t + 512]);
}

// --------------------------------------------- weight transpose + convert ---
// w [K][N] fp32 -> wt [N][K] bf16 (N bounds-guarded; K must be %32)
__global__ __launch_bounds__(256) void transpose_bf16_k(const float* __restrict__ w,
                                                        bf16_t* __restrict__ wt,
                                                        int K, int N) {
    __shared__ float t[32][33];
    int bx = blockIdx.x * 32, by = blockIdx.y * 32;
    int tx = threadIdx.x & 31, ty = threadIdx.x >> 5;
#pragma unroll
    for (int i = 0; i < 32; i += 8)
        if (bx + tx < N)
            t[ty + i][tx] = w[(size_t)(by + ty + i) * N + bx + tx];
    __syncthreads();
#pragma unroll
    for (int i = 0; i < 32; i += 8)
        if (bx + ty + i < N)
            wt[(size_t)(bx + ty + i) * K + by + tx] = __float2bfloat16(t[tx][ty + i]);
}

// -------------------------- dt_proj operand prep (pad K 48 -> 64, bf16) -----
// xdbl[:, 0:48] fp32 -> dtlo [8192][64] bf16, cols 48..63 zero
__global__ __launch_bounds__(256) void pad_dtlo_k(const float* __restrict__ xdbl,
                                                  bf16_t* __restrict__ dtlo) {
    int idx = blockIdx.x * 256 + threadIdx.x;
    int row = idx >> 6, k = idx & 63;
    float v = (k < DT_RANK) ? xdbl[(size_t)row * 80 + k] : 0.f;
    dtlo[idx] = __float2bfloat16(v);
}
// dtpw [48][1536] fp32 -> wdt [1536][64] bf16, cols 48..63 zero
__global__ __launch_bounds__(256) void pad_dtw_k(const float* __restrict__ dtpw,
                                                 bf16_t* __restrict__ wdt) {
    int idx = blockIdx.x * 256 + threadIdx.x;   // n*64 + k
    int n = idx >> 6, k = idx & 63;
    float v = (k < DT_RANK) ? dtpw[(size_t)k * D_INNER + n] : 0.f;
    wdt[idx] = __float2bfloat16(v);
}

// ------------------------------------------------------- bf16 MFMA GEMM -----
// C[M,N] = A[M,K] * Bt[N,K]^T.  A,Bt bf16 row-major, K % 64 == 0.
// EPI 2: fp32 store acc + aux[row*N+col].  EPI 3: bf16 store.
// EPI 4: fp32 store softplus(acc + aux[col]).
template <int EPI>
__global__ __launch_bounds__(256) void mfma_gemm_k(const bf16_t* __restrict__ A,
                                                   const bf16_t* __restrict__ Bt,
                                                   void* __restrict__ Cv,
                                                   int M, int N, int K,
                                                   const float* __restrict__ aux) {
    __shared__ bf16_t As[128][64];
    __shared__ bf16_t Bs[128][64];
    const int tid = threadIdx.x;
    const int lane = tid & 63, wid = tid >> 6;
    const int bm = blockIdx.y * 128, bn = blockIdx.x * 128;
    const int wm = wid >> 1, wn = wid & 1;
    f32x4 acc[4][4] = {};
    for (int k0 = 0; k0 < K; k0 += 64) {
#pragma unroll
        for (int i = 0; i < 4; i++) {
            int idx = tid + i * 256;
            int r = idx >> 3, c = idx & 7;
            gload16(A + (size_t)(bm + r) * K + k0 + ((c ^ (r & 7)) << 3),
                    (bf16_t*)As + idx * 8);
        }
#pragma unroll
        for (int i = 0; i < 4; i++) {
            int idx = tid + i * 256;
            int r = idx >> 3, c = idx & 7;
            gload16(Bt + (size_t)(bn + r) * K + k0 + ((c ^ (r & 7)) << 3),
                    (bf16_t*)Bs + idx * 8);
        }
        asm volatile("s_waitcnt vmcnt(0)" ::: "memory");
        __syncthreads();
#pragma unroll
        for (int ks = 0; ks < 2; ks++) {
            bf16x8 af[4], bfr[4];
#pragma unroll
            for (int i = 0; i < 4; i++) {
                int row = wm * 64 + i * 16 + (lane & 15);
                int cl = ks * 4 + (lane >> 4);
                af[i] = *(const bf16x8*)(&As[row][(cl ^ (row & 7)) << 3]);
            }
#pragma unroll
            for (int j = 0; j < 4; j++) {
                int row = wn * 64 + j * 16 + (lane & 15);
                int cl = ks * 4 + (lane >> 4);
                bfr[j] = *(const bf16x8*)(&Bs[row][(cl ^ (row & 7)) << 3]);
            }
#pragma unroll
            for (int i = 0; i < 4; i++)
#pragma unroll
                for (int j = 0; j < 4; j++)
                    acc[i][j] = __builtin_amdgcn_mfma_f32_16x16x32_bf16(
                        af[i], bfr[j], acc[i][j], 0, 0, 0);
        }
        __syncthreads();
    }
#pragma unroll
    for (int i = 0; i < 4; i++) {
#pragma unroll
        for (int j = 0; j < 4; j++) {
#pragma unroll
            for (int q = 0; q < 4; q++) {
                int row = bm + wm * 64 + i * 16 + (lane >> 4) * 4 + q;
                int col = bn + wn * 64 + j * 16 + (lane & 15);
                float v = acc[i][j][q];
                if (EPI == 2) {
                    ((float*)Cv)[(size_t)row * N + col] = v + aux[(size_t)row * N + col];
                } else if (EPI == 4) {
                    ((float*)Cv)[(size_t)row * N + col] = softplusf(v + aux[col]);
                } else {
                    ((bf16_t*)Cv)[(size_t)row * N + col] = __float2bfloat16(v);
                }
            }
        }
    }
}

// --------------------------------------- x_proj: split-K skinny MFMA GEMM ---
// C[8192][80] += A[8192][1536]bf16 * Bt[80][1536]^T, K split 8 ways, atomicAdd.
__global__ __launch_bounds__(256) void xproj_k(const bf16_t* __restrict__ A,
                                               const bf16_t* __restrict__ Bt,
                                               float* __restrict__ C) {
    __shared__ bf16_t As[64][64];
    __shared__ bf16_t Bs[80][64];
    const int tid = threadIdx.x;
    const int lane = tid & 63, wid = tid >> 6;   // 4 waves
    const int bm = blockIdx.x * 64;
    const int k0base = blockIdx.y * XP_KR;
    f32x4 acc[5] = {};
    for (int kt = 0; kt < XP_KR; kt += 64) {
        int k0 = k0base + kt;
#pragma unroll
        for (int i = 0; i < 2; i++) {            // A: 512 chunks
            int idx = tid + i * 256;
            int r = idx >> 3, c = idx & 7;
            gload16(A + (size_t)(bm + r) * D_INNER + k0 + ((c ^ (r & 7)) << 3),
                    (bf16_t*)As + idx * 8);
        }
#pragma unroll
        for (int i = 0; i < 3; i++) {            // B: 640 chunks (wave-uniform guard)
            int idx = tid + i * 256;
            if (idx < 640) {
                int r = idx >> 3, c = idx & 7;
                gload16(Bt + (size_t)r * D_INNER + k0 + ((c ^ (r & 7)) << 3),
                        (bf16_t*)Bs + idx * 8);
            }
        }
        asm volatile("s_waitcnt vmcnt(0)" ::: "memory");
        __syncthreads();
#pragma unroll
        for (int ks = 0; ks < 2; ks++) {
            int arow = wid * 16 + (lane & 15);
            int cl = ks * 4 + (lane >> 4);
            bf16x8 af = *(const bf16x8*)(&As[arow][(cl ^ (arow & 7)) << 3]);
#pragma unroll
            for (int j = 0; j < 5; j++) {
                int brow = j * 16 + (lane & 15);
                bf16x8 bf_ = *(const bf16x8*)(&Bs[brow][(cl ^ (brow & 7)) << 3]);
                acc[j] = __builtin_amdgcn_mfma_f32_16x16x32_bf16(af, bf_, acc[j], 0, 0, 0);
            }
        }
        __syncthreads();
    }
#pragma unroll
    for (int j = 0; j < 5; j++)
#pragma unroll
        for (int q = 0; q < 4; q++) {
            int row = bm + wid * 16 + (lane >> 4) * 4 + q;
            int col = j * 16 + (lane & 15);
            atomicAdd(&C[(size_t)row * 80 + col], acc[j][q]);
        }
}

// -------------------------------------------------- depthwise conv + SiLU ---
__global__ __launch_bounds__(256) void conv_silu_k(const bf16_t* __restrict__ xz,
                                                   const float* __restrict__ cw,
                                                   const float* __restrict__ cb,
                                                   bf16_t* __restrict__ xi) {
    int idx = blockIdx.x * 256 + threadIdx.x;
    int d = idx % D_INNER;
    int row = idx / D_INNER;   // b*NL + l
    int l = row % NL;
    float w0 = cw[d * 4 + 0], w1 = cw[d * 4 + 1];
    float w2 = cw[d * 4 + 2], w3 = cw[d * 4 + 3];
    const bf16_t* base = xz + (size_t)row * (2 * D_INNER) + d;
    float acc = cb[d] + w3 * __bfloat162float(base[0]);
    if (l >= 1) acc += w2 * __bfloat162float(base[-(ptrdiff_t)(2 * D_INNER)]);
    if (l >= 2) acc += w1 * __bfloat162float(base[-(ptrdiff_t)(4 * D_INNER)]);
    if (l >= 3) acc += w0 * __bfloat162float(base[-(ptrdiff_t)(6 * D_INNER)]);
    xi[idx] = __float2bfloat16(siluf(acc));
}

// --------------------------------------------------- scan phase A: carries --
__global__ __launch_bounds__(256) void scanA_k(const float* __restrict__ dtb,
                                               const bf16_t* __restrict__ xi,
                                               const float* __restrict__ xdbl,
                                               const float* __restrict__ A_log,
                                               float* __restrict__ hend,
                                               float* __restrict__ dtsum) {
    __shared__ float Bsh[CHUNK][16];
    const int d = blockIdx.x * 256 + threadIdx.x;
    const int c = blockIdx.y, b = blockIdx.z;
    const size_t rowbase = (size_t)b * NL + (size_t)c * CHUNK;
    const float* bsrc = xdbl + rowbase * 80 + DT_RANK;
    {
        int i = threadIdx.x;           // CHUNK*4 == 256
        int row = i >> 2, c4 = i & 3;
        *(float4*)&Bsh[row][c4 * 4] = *(const float4*)&bsrc[(size_t)row * 80 + c4 * 4];
    }
    __syncthreads();
    float Av[16];
#pragma unroll
    for (int q = 0; q < 4; q++) {
        float4 a4 = *(const float4*)&A_log[(size_t)d * 16 + q * 4];
        Av[q * 4 + 0] = -__expf(a4.x);
        Av[q * 4 + 1] = -__expf(a4.y);
        Av[q * 4 + 2] = -__expf(a4.z);
        Av[q * 4 + 3] = -__expf(a4.w);
    }
    float h[16];
#pragma unroll
    for (int s = 0; s < 16; s++) h[s] = 0.f;
    float dts = 0.f;
    const float* dtp = dtb + rowbase * D_INNER + d;
    const bf16_t* xp = xi + rowbase * D_INNER + d;
    float dt_n = dtp[0];
    bf16_t x_n = xp[0];
    for (int l = 0; l < CHUNK; l++) {
        float dt_c = dt_n, x_c = __bfloat162float(x_n);
        if (l + 1 < CHUNK) {
            dt_n = dtp[(size_t)(l + 1) * D_INNER];
            x_n  = xp[(size_t)(l + 1) * D_INNER];
        }
        float4 b0 = *(const float4*)&Bsh[l][0];
        float4 b1 = *(const float4*)&Bsh[l][4];
        float4 b2 = *(const float4*)&Bsh[l][8];
        float4 b3 = *(const float4*)&Bsh[l][12];
        float Bv[16] = {b0.x, b0.y, b0.z, b0.w, b1.x, b1.y, b1.z, b1.w,
                        b2.x, b2.y, b2.z, b2.w, b3.x, b3.y, b3.z, b3.w};
        float dtx = dt_c * x_c;
#pragma unroll
        for (int s = 0; s < 16; s++)
            h[s] = h[s] * __expf(dt_c * Av[s]) + dtx * Bv[s];
        dts += dt_c;
    }
    size_t gi = ((size_t)(b * NCHUNK + c) * D_INNER + d) * 16;
#pragma unroll
    for (int q = 0; q < 4; q++)
        *(float4*)&hend[gi + q * 4] =
            make_float4(h[q * 4], h[q * 4 + 1], h[q * 4 + 2], h[q * 4 + 3]);
    dtsum[gi >> 4] = dts;
}

// --------------------------------------------- scan phase B: combine carries -
__global__ __launch_bounds__(256) void scanB_k(const float* __restrict__ hend,
                                               const float* __restrict__ dtsum,
                                               const float* __restrict__ A_log,
                                               float* __restrict__ carry) {
    int t = blockIdx.x * 256 + threadIdx.x;   // (b*D_INNER+d)*16+s
    int s = t & 15;
    int bd = t >> 4;
    int b = bd / D_INNER, d = bd % D_INNER;
    float Av = -__expf(A_log[d * D_STATE + s]);
    float h = 0.f;
    for (int c = 0; c < NCHUNK; c++) {
        size_t gi = (size_t)(b * NCHUNK + c) * D_INNER + d;
        carry[gi * 16 + s] = h;
        h = h * __expf(Av * dtsum[gi]) + hend[gi * 16 + s];
    }
}

// ------------------------------- scan phase C: full scan + gating, y -> bf16 -
__global__ __launch_bounds__(256) void scanC_k(const float* __restrict__ dtb,
                                               const bf16_t* __restrict__ xi,
                                               const float* __restrict__ xdbl,
                                               const bf16_t* __restrict__ xz,
                                               const float* __restrict__ A_log,
                                               const float* __restrict__ Dp,
                                               const float* __restrict__ carry,
                                               bf16_t* __restrict__ yb) {
    __shared__ float BC[CHUNK][32];
    const int d = blockIdx.x * 256 + threadIdx.x;
    const int c = blockIdx.y, b = blockIdx.z;
    const size_t rowbase = (size_t)b * NL + (size_t)c * CHUNK;
    const float* src = xdbl + rowbase * 80 + DT_RANK;
#pragma unroll
    for (int ii = 0; ii < 2; ii++) {      // CHUNK*8 == 512 float4s
        int i = threadIdx.x + ii * 256;
        int row = i >> 3, c4 = i & 7;
        *(float4*)&BC[row][c4 * 4] = *(const float4*)&src[(size_t)row * 80 + c4 * 4];
    }
    __syncthreads();
    float Av[16];
#pragma unroll
    for (int q = 0; q < 4; q++) {
        float4 a4 = *(const float4*)&A_log[(size_t)d * 16 + q * 4];
        Av[q * 4 + 0] = -__expf(a4.x);
        Av[q * 4 + 1] = -__expf(a4.y);
        Av[q * 4 + 2] = -__expf(a4.z);
        Av[q * 4 + 3] = -__expf(a4.w);
    }
    float Dd = Dp[d];
    float h[16];
    size_t gi = ((size_t)(b * NCHUNK + c) * D_INNER + d) * 16;
#pragma unroll
    for (int q = 0; q < 4; q++) {
        float4 c4v = *(const float4*)&carry[gi + q * 4];
        h[q * 4 + 0] = c4v.x; h[q * 4 + 1] = c4v.y;
        h[q * 4 + 2] = c4v.z; h[q * 4 + 3] = c4v.w;
    }
    const float* dtp = dtb + rowbase * D_INNER + d;
    const bf16_t* xp = xi + rowbase * D_INNER + d;
    const bf16_t* zp = xz + rowbase * (2 * D_INNER) + D_INNER + d;
    bf16_t* yp = yb + rowbase * D_INNER + d;
    float dt_n = dtp[0];
    bf16_t x_n = xp[0], z_n = zp[0];
    for (int l = 0; l < CHUNK; l++) {
        float dt_c = dt_n, x_c = __bfloat162float(x_n);
        float z_c = __bfloat162float(z_n);
        if (l + 1 < CHUNK) {
            dt_n = dtp[(size_t)(l + 1) * D_INNER];
            x_n  = xp[(size_t)(l + 1) * D_INNER];
            z_n  = zp[(size_t)(l + 1) * (2 * D_INNER)];
        }
        float4 b0 = *(const float4*)&BC[l][0];
        float4 b1 = *(const float4*)&BC[l][4];
        float4 b2 = *(const float4*)&BC[l][8];
        float4 b3 = *(const float4*)&BC[l][12];
        float4 c0 = *(const float4*)&BC[l][16];
        float4 c1 = *(const float4*)&BC[l][20];
        float4 c2 = *(const float4*)&BC[l][24];
        float4 c3 = *(const float4*)&BC[l][28];
        float Bv[16] = {b0.x, b0.y, b0.z, b0.w, b1.x, b1.y, b1.z, b1.w,
                        b2.x, b2.y, b2.z, b2.w, b3.x, b3.y, b3.z, b3.w};
        float Cv[16] = {c0.x, c0.y, c0.z, c0.w, c1.x, c1.y, c1.z, c1.w,
                        c2.x, c2.y, c2.z, c2.w, c3.x, c3.y, c3.z, c3.w};
        float dtx = dt_c * x_c;
        float p = Dd * x_c;
#pragma unroll
        for (int s = 0; s < 16; s++) {
            h[s] = h[s] * __expf(dt_c * Av[s]) + dtx * Bv[s];
            p += h[s] * Cv[s];
        }
        yp[(size_t)l * D_INNER] = __float2bfloat16(p * siluf(z_c));
    }
}

// ----------------------------------------------------------------- launch ---
extern "C" void kernel_launch(void* const* d_in, const int* in_sizes, int n_in,
                              void* d_out, int out_size, void* d_ws, size_t ws_size,
                              hipStream_t stream) {
    const float* seq    = (const float*)d_in[0];
    const float* normw  = (const float*)d_in[1];
    const float* inpw   = (const float*)d_in[2];
    const float* convw  = (const float*)d_in[3];
    const float* convb  = (const float*)d_in[4];
    const float* xprojw = (const float*)d_in[5];
    const float* dtpw   = (const float*)d_in[6];
    const float* dtbias = (const float*)d_in[7];
    const float* Alog   = (const float*)d_in[8];
    const float* Dp     = (const float*)d_in[9];
    const float* outpw  = (const float*)d_in[10];
    float* out = (float*)d_out;

    float* ws = (float*)d_ws;
    bf16_t* xi_bf = (bf16_t*)ws;             // 8192*1536 bf16 (half of slot)
    float* dt    = ws + 12582912;            // 12582912 f
    float* xdbl  = dt + 12582912;            // 8192*80    = 655360 f
    float* hend  = xdbl + 655360;            // 4*32*1536*16 = 3145728 f
    float* carry = hend + 3145728;           // 3145728 f
    float* dtsum = carry + 3145728;          // 4*32*1536  = 196608 f
    bf16_t* xz_bf    = (bf16_t*)(dtsum + 196608);  // 8192*3072 = 25165824 bf16
    bf16_t* xnorm_bf = xz_bf + 25165824;           // 8192*768  = 6291456
    bf16_t* y_bf     = xnorm_bf + 6291456;         // 8192*1536 = 12582912
    bf16_t* w1t      = y_bf + 12582912;            // 3072*768  = 2359296
    bf16_t* w4t      = w1t + 2359296;              // 768*1536  = 1179648
    bf16_t* wxt      = w4t + 1179648;              // 80*1536   = 122880
    bf16_t* wdt      = wxt + 122880;               // 1536*64   = 98304
    bf16_t* dtlo     = wdt + 98304;                // 8192*64   = 524288

    // 1. RMSNorm (bf16 out)
    rmsnorm_k<<<NROWS, 256, 0, stream>>>(seq, normw, xnorm_bf);

    // 1b. weight transposes -> bf16 [N][K]
    transpose_bf16_k<<<dim3(3072 / 32, 768 / 32), 256, 0, stream>>>(inpw, w1t, D_MODEL, 2 * D_INNER);
    transpose_bf16_k<<<dim3(768 / 32, 1536 / 32), 256, 0, stream>>>(outpw, w4t, D_INNER, D_MODEL);
    transpose_bf16_k<<<dim3(3, 1536 / 32), 256, 0, stream>>>(xprojw, wxt, D_INNER, 80);
    pad_dtw_k<<<(D_INNER * 64) / 256, 256, 0, stream>>>(dtpw, wdt);

    // zero xdbl for the split-K atomic accumulation
    hipMemsetAsync(xdbl, 0, (size_t)NROWS * 80 * sizeof(float), stream);

    // 2. in_proj (MFMA): xz_bf = xnorm @ in_proj_w   [8192 x 3072, K=768]
    mfma_gemm_k<3><<<dim3(3072 / 128, NROWS / 128), 256, 0, stream>>>(
        xnorm_bf, w1t, xz_bf, NROWS, 2 * D_INNER, D_MODEL, nullptr);

    // 3. depthwise conv + SiLU -> xi (bf16)
    conv_silu_k<<<(NROWS * D_INNER) / 256, 256, 0, stream>>>(xz_bf, convw, convb, xi_bf);

    // 4. x_proj (split-K MFMA, atomic): xdbl = xi @ x_proj_w  [8192 x 80, K=1536]
    xproj_k<<<dim3(NROWS / 64, XP_SPLIT), 256, 0, stream>>>(xi_bf, wxt, xdbl);

    // 5. dt_proj (MFMA, K padded 48->64) + softplus -> fp32 dt
    pad_dtlo_k<<<(NROWS * 64) / 256, 256, 0, stream>>>(xdbl, dtlo);
    mfma_gemm_k<4><<<dim3(D_INNER / 128, NROWS / 128), 256, 0, stream>>>(
        dtlo, wdt, dt, NROWS, D_INNER, 64, dtbias);

    // 6. chunked selective scan (lane-per-channel, h[16] in registers)
    scanA_k<<<dim3(D_INNER / 256, NCHUNK, NB), 256, 0, stream>>>(dt, xi_bf, xdbl, Alog, hend, dtsum);
    scanB_k<<<(NB * D_INNER * 16) / 256, 256, 0, stream>>>(hend, dtsum, Alog, carry);
    scanC_k<<<dim3(D_INNER / 256, NCHUNK, NB), 256, 0, stream>>>(dt, xi_bf, xdbl, xz_bf, Alog, Dp,
                                                                 carry, y_bf);

    // 7. out_proj (MFMA) + residual: out = y @ out_proj_w + seq
    mfma_gemm_k<2><<<dim3(D_MODEL / 128, NROWS / 128), 256, 0, stream>>>(
        y_bf, w4t, out, NROWS, D_MODEL, D_INNER, seq);
}

// Round 14
// 414.082 us; speedup vs baseline: 6.7722x; 1.0223x over previous
//
#include <hip/hip_runtime.h>
#include <hip/hip_bf16.h>
#include <cstdint>
#include <cstddef>

#define D_MODEL 768
#define D_STATE 16
#define D_CONV  4
#define D_INNER 1536
#define DT_RANK 48
#define NB      4
#define NL      2048
#define NROWS   (NB * NL)   // 8192
#define EPS     1e-5f
#define NCHUNK  64
#define CHUNK   (NL / NCHUNK)   // 32
#define XP_SPLIT 8
#define XP_KR   (D_INNER / XP_SPLIT)   // 192
#define LOG2E   1.44269504088896f

typedef __bf16 bf16x8 __attribute__((ext_vector_type(8)));
typedef float  f32x4  __attribute__((ext_vector_type(4)));
typedef __hip_bfloat16 bf16_t;

#if __has_builtin(__builtin_amdgcn_exp2f)
#define EXP2F(x) __builtin_amdgcn_exp2f(x)
#else
#define EXP2F(x) exp2f(x)
#endif

__device__ __forceinline__ float siluf(float x) { return x / (1.f + __expf(-x)); }
__device__ __forceinline__ float softplusf(float x) {
    return x > 20.f ? x : log1pf(__expf(x));
}
__device__ __forceinline__ void gload16(const void* g, void* l) {
    __builtin_amdgcn_global_load_lds((const __attribute__((address_space(1))) unsigned int*)g,
                                     (__attribute__((address_space(3))) unsigned int*)l, 16, 0, 0);
}

// ---------------------------------------------------------------- RMSNorm ---
__global__ __launch_bounds__(256) void rmsnorm_k(const float* __restrict__ seq,
                                                 const float* __restrict__ w,
                                                 bf16_t* __restrict__ out) {
    int row = blockIdx.x;
    const float* x = seq + (size_t)row * D_MODEL;
    bf16_t* o = out + (size_t)row * D_MODEL;
    int t = threadIdx.x;
    float v0 = x[t], v1 = x[t + 256], v2 = x[t + 512];
    float ss = v0 * v0 + v1 * v1 + v2 * v2;
#pragma unroll
    for (int off = 32; off; off >>= 1) ss += __shfl_down(ss, off, 64);
    __shared__ float parts[4];
    if ((t & 63) == 0) parts[t >> 6] = ss;
    __syncthreads();
    float tot = parts[0] + parts[1] + parts[2] + parts[3];
    float rs = rsqrtf(tot / (float)D_MODEL + EPS);
    o[t]       = __float2bfloat16(v0 * rs * w[t]);
    o[t + 256] = __float2bfloat16(v1 * rs * w[t + 256]);
    o[t + 512] = __float2bfloat16(v2 * rs * w[t + 512]);
}

// --------------------------------------------- weight transpose + convert ---
// w [K][N] fp32 -> wt [N][K] bf16 (N bounds-guarded; K must be %32)
__global__ __launch_bounds__(256) void transpose_bf16_k(const float* __restrict__ w,
                                                        bf16_t* __restrict__ wt,
                                                        int K, int N) {
    __shared__ float t[32][33];
    int bx = blockIdx.x * 32, by = blockIdx.y * 32;
    int tx = threadIdx.x & 31, ty = threadIdx.x >> 5;
#pragma unroll
    for (int i = 0; i < 32; i += 8)
        if (bx + tx < N)
            t[ty + i][tx] = w[(size_t)(by + ty + i) * N + bx + tx];
    __syncthreads();
#pragma unroll
    for (int i = 0; i < 32; i += 8)
        if (bx + ty + i < N)
            wt[(size_t)(bx + ty + i) * K + by + tx] = __float2bfloat16(t[tx][ty + i]);
}

// -------------------------- dt_proj operand prep (pad K 48 -> 64, bf16) -----
__global__ __launch_bounds__(256) void pad_dtlo_k(const float* __restrict__ xdbl,
                                                  bf16_t* __restrict__ dtlo) {
    int idx = blockIdx.x * 256 + threadIdx.x;
    int row = idx >> 6, k = idx & 63;
    float v = (k < DT_RANK) ? xdbl[(size_t)row * 80 + k] : 0.f;
    dtlo[idx] = __float2bfloat16(v);
}
__global__ __launch_bounds__(256) void pad_dtw_k(const float* __restrict__ dtpw,
                                                 bf16_t* __restrict__ wdt) {
    int idx = blockIdx.x * 256 + threadIdx.x;   // n*64 + k
    int n = idx >> 6, k = idx & 63;
    float v = (k < DT_RANK) ? dtpw[(size_t)k * D_INNER + n] : 0.f;
    wdt[idx] = __float2bfloat16(v);
}

// ------------------------------------------------------- bf16 MFMA GEMM -----
// C[M,N] = A[M,K] * Bt[N,K]^T.  A,Bt bf16 row-major, K % 64 == 0.
// EPI 2: fp32 store acc + aux[row*N+col].  EPI 3: bf16 store.
// EPI 5: bf16 store softplus(acc + aux[col]).
template <int EPI>
__global__ __launch_bounds__(256) void mfma_gemm_k(const bf16_t* __restrict__ A,
                                                   const bf16_t* __restrict__ Bt,
                                                   void* __restrict__ Cv,
                                                   int M, int N, int K,
                                                   const float* __restrict__ aux) {
    __shared__ bf16_t As[128][64];
    __shared__ bf16_t Bs[128][64];
    const int tid = threadIdx.x;
    const int lane = tid & 63, wid = tid >> 6;
    const int bm = blockIdx.y * 128, bn = blockIdx.x * 128;
    const int wm = wid >> 1, wn = wid & 1;
    f32x4 acc[4][4] = {};
    for (int k0 = 0; k0 < K; k0 += 64) {
#pragma unroll
        for (int i = 0; i < 4; i++) {
            int idx = tid + i * 256;
            int r = idx >> 3, c = idx & 7;
            gload16(A + (size_t)(bm + r) * K + k0 + ((c ^ (r & 7)) << 3),
                    (bf16_t*)As + idx * 8);
        }
#pragma unroll
        for (int i = 0; i < 4; i++) {
            int idx = tid + i * 256;
            int r = idx >> 3, c = idx & 7;
            gload16(Bt + (size_t)(bn + r) * K + k0 + ((c ^ (r & 7)) << 3),
                    (bf16_t*)Bs + idx * 8);
        }
        asm volatile("s_waitcnt vmcnt(0)" ::: "memory");
        __syncthreads();
#pragma unroll
        for (int ks = 0; ks < 2; ks++) {
            bf16x8 af[4], bfr[4];
#pragma unroll
            for (int i = 0; i < 4; i++) {
                int row = wm * 64 + i * 16 + (lane & 15);
                int cl = ks * 4 + (lane >> 4);
                af[i] = *(const bf16x8*)(&As[row][(cl ^ (row & 7)) << 3]);
            }
#pragma unroll
            for (int j = 0; j < 4; j++) {
                int row = wn * 64 + j * 16 + (lane & 15);
                int cl = ks * 4 + (lane >> 4);
                bfr[j] = *(const bf16x8*)(&Bs[row][(cl ^ (row & 7)) << 3]);
            }
#pragma unroll
            for (int i = 0; i < 4; i++)
#pragma unroll
                for (int j = 0; j < 4; j++)
                    acc[i][j] = __builtin_amdgcn_mfma_f32_16x16x32_bf16(
                        af[i], bfr[j], acc[i][j], 0, 0, 0);
        }
        __syncthreads();
    }
#pragma unroll
    for (int i = 0; i < 4; i++) {
#pragma unroll
        for (int j = 0; j < 4; j++) {
#pragma unroll
            for (int q = 0; q < 4; q++) {
                int row = bm + wm * 64 + i * 16 + (lane >> 4) * 4 + q;
                int col = bn + wn * 64 + j * 16 + (lane & 15);
                float v = acc[i][j][q];
                if (EPI == 2) {
                    ((float*)Cv)[(size_t)row * N + col] = v + aux[(size_t)row * N + col];
                } else if (EPI == 5) {
                    ((bf16_t*)Cv)[(size_t)row * N + col] =
                        __float2bfloat16(softplusf(v + aux[col]));
                } else {
                    ((bf16_t*)Cv)[(size_t)row * N + col] = __float2bfloat16(v);
                }
            }
        }
    }
}

// --------------------------------------- x_proj: split-K skinny MFMA GEMM ---
__global__ __launch_bounds__(256) void xproj_k(const bf16_t* __restrict__ A,
                                               const bf16_t* __restrict__ Bt,
                                               float* __restrict__ C) {
    __shared__ bf16_t As[64][64];
    __shared__ bf16_t Bs[80][64];
    const int tid = threadIdx.x;
    const int lane = tid & 63, wid = tid >> 6;   // 4 waves
    const int bm = blockIdx.x * 64;
    const int k0base = blockIdx.y * XP_KR;
    f32x4 acc[5] = {};
    for (int kt = 0; kt < XP_KR; kt += 64) {
        int k0 = k0base + kt;
#pragma unroll
        for (int i = 0; i < 2; i++) {            // A: 512 chunks
            int idx = tid + i * 256;
            int r = idx >> 3, c = idx & 7;
            gload16(A + (size_t)(bm + r) * D_INNER + k0 + ((c ^ (r & 7)) << 3),
                    (bf16_t*)As + idx * 8);
        }
#pragma unroll
        for (int i = 0; i < 3; i++) {            // B: 640 chunks
            int idx = tid + i * 256;
            if (idx < 640) {
                int r = idx >> 3, c = idx & 7;
                gload16(Bt + (size_t)r * D_INNER + k0 + ((c ^ (r & 7)) << 3),
                        (bf16_t*)Bs + idx * 8);
            }
        }
        asm volatile("s_waitcnt vmcnt(0)" ::: "memory");
        __syncthreads();
#pragma unroll
        for (int ks = 0; ks < 2; ks++) {
            int arow = wid * 16 + (lane & 15);
            int cl = ks * 4 + (lane >> 4);
            bf16x8 af = *(const bf16x8*)(&As[arow][(cl ^ (arow & 7)) << 3]);
#pragma unroll
            for (int j = 0; j < 5; j++) {
                int brow = j * 16 + (lane & 15);
                bf16x8 bf_ = *(const bf16x8*)(&Bs[brow][(cl ^ (brow & 7)) << 3]);
                acc[j] = __builtin_amdgcn_mfma_f32_16x16x32_bf16(af, bf_, acc[j], 0, 0, 0);
            }
        }
        __syncthreads();
    }
#pragma unroll
    for (int j = 0; j < 5; j++)
#pragma unroll
        for (int q = 0; q < 4; q++) {
            int row = bm + wid * 16 + (lane >> 4) * 4 + q;
            int col = j * 16 + (lane & 15);
            atomicAdd(&C[(size_t)row * 80 + col], acc[j][q]);
        }
}

// -------------------------------------------------- depthwise conv + SiLU ---
__global__ __launch_bounds__(256) void conv_silu_k(const bf16_t* __restrict__ xz,
                                                   const float* __restrict__ cw,
                                                   const float* __restrict__ cb,
                                                   bf16_t* __restrict__ xi) {
    int idx = blockIdx.x * 256 + threadIdx.x;
    int d = idx % D_INNER;
    int row = idx / D_INNER;   // b*NL + l
    int l = row % NL;
    float w0 = cw[d * 4 + 0], w1 = cw[d * 4 + 1];
    float w2 = cw[d * 4 + 2], w3 = cw[d * 4 + 3];
    const bf16_t* base = xz + (size_t)row * (2 * D_INNER) + d;
    float acc = cb[d] + w3 * __bfloat162float(base[0]);
    if (l >= 1) acc += w2 * __bfloat162float(base[-(ptrdiff_t)(2 * D_INNER)]);
    if (l >= 2) acc += w1 * __bfloat162float(base[-(ptrdiff_t)(4 * D_INNER)]);
    if (l >= 3) acc += w0 * __bfloat162float(base[-(ptrdiff_t)(6 * D_INNER)]);
    xi[idx] = __float2bfloat16(siluf(acc));
}

// --------------------------------------------------- scan phase A: carries --
// ONE LANE per (b, chunk, d); Av pre-scaled by log2e, exp2 native; dt/xi bf16.
__global__ __launch_bounds__(256) void scanA_k(const bf16_t* __restrict__ dtb,
                                               const bf16_t* __restrict__ xi,
                                               const float* __restrict__ xdbl,
                                               const float* __restrict__ A_log,
                                               float* __restrict__ hend,
                                               float* __restrict__ dtsum) {
    __shared__ float Bsh[CHUNK][16];
    const int d = blockIdx.x * 256 + threadIdx.x;
    const int c = blockIdx.y, b = blockIdx.z;
    const size_t rowbase = (size_t)b * NL + (size_t)c * CHUNK;
    const float* bsrc = xdbl + rowbase * 80 + DT_RANK;
    if (threadIdx.x < CHUNK * 4) {            // 128 float4s
        int i = threadIdx.x;
        int row = i >> 2, c4 = i & 3;
        *(float4*)&Bsh[row][c4 * 4] = *(const float4*)&bsrc[(size_t)row * 80 + c4 * 4];
    }
    __syncthreads();
    float Av[16];
#pragma unroll
    for (int q = 0; q < 4; q++) {
        float4 a4 = *(const float4*)&A_log[(size_t)d * 16 + q * 4];
        Av[q * 4 + 0] = -__expf(a4.x) * LOG2E;
        Av[q * 4 + 1] = -__expf(a4.y) * LOG2E;
        Av[q * 4 + 2] = -__expf(a4.z) * LOG2E;
        Av[q * 4 + 3] = -__expf(a4.w) * LOG2E;
    }
    float h[16];
#pragma unroll
    for (int s = 0; s < 16; s++) h[s] = 0.f;
    float dts = 0.f;
    const bf16_t* dtp = dtb + rowbase * D_INNER + d;
    const bf16_t* xp  = xi + rowbase * D_INNER + d;
    bf16_t dt_n = dtp[0], x_n = xp[0];
    for (int l = 0; l < CHUNK; l++) {
        float dt_c = __bfloat162float(dt_n), x_c = __bfloat162float(x_n);
        if (l + 1 < CHUNK) {
            dt_n = dtp[(size_t)(l + 1) * D_INNER];
            x_n  = xp[(size_t)(l + 1) * D_INNER];
        }
        float4 b0 = *(const float4*)&Bsh[l][0];
        float4 b1 = *(const float4*)&Bsh[l][4];
        float4 b2 = *(const float4*)&Bsh[l][8];
        float4 b3 = *(const float4*)&Bsh[l][12];
        float Bv[16] = {b0.x, b0.y, b0.z, b0.w, b1.x, b1.y, b1.z, b1.w,
                        b2.x, b2.y, b2.z, b2.w, b3.x, b3.y, b3.z, b3.w};
        float dtx = dt_c * x_c;
#pragma unroll
        for (int s = 0; s < 16; s++)
            h[s] = h[s] * EXP2F(dt_c * Av[s]) + dtx * Bv[s];
        dts += dt_c;
    }
    size_t gi = ((size_t)(b * NCHUNK + c) * D_INNER + d) * 16;
#pragma unroll
    for (int q = 0; q < 4; q++)
        *(float4*)&hend[gi + q * 4] =
            make_float4(h[q * 4], h[q * 4 + 1], h[q * 4 + 2], h[q * 4 + 3]);
    dtsum[gi >> 4] = dts;
}

// --------------------------------------------- scan phase B: combine carries -
__global__ __launch_bounds__(256) void scanB_k(const float* __restrict__ hend,
                                               const float* __restrict__ dtsum,
                                               const float* __restrict__ A_log,
                                               float* __restrict__ carry) {
    int t = blockIdx.x * 256 + threadIdx.x;   // (b*D_INNER+d)*16+s
    int s = t & 15;
    int bd = t >> 4;
    int b = bd / D_INNER, d = bd % D_INNER;
    float Av2 = -__expf(A_log[d * D_STATE + s]) * LOG2E;
    float h = 0.f;
    for (int c = 0; c < NCHUNK; c++) {
        size_t gi = (size_t)(b * NCHUNK + c) * D_INNER + d;
        carry[gi * 16 + s] = h;
        h = h * EXP2F(Av2 * dtsum[gi]) + hend[gi * 16 + s];
    }
}

// ------------------------------- scan phase C: full scan + gating, y -> bf16 -
__global__ __launch_bounds__(256) void scanC_k(const bf16_t* __restrict__ dtb,
                                               const bf16_t* __restrict__ xi,
                                               const float* __restrict__ xdbl,
                                               const bf16_t* __restrict__ xz,
                                               const float* __restrict__ A_log,
                                               const float* __restrict__ Dp,
                                               const float* __restrict__ carry,
                                               bf16_t* __restrict__ yb) {
    __shared__ float BC[CHUNK][32];
    const int d = blockIdx.x * 256 + threadIdx.x;
    const int c = blockIdx.y, b = blockIdx.z;
    const size_t rowbase = (size_t)b * NL + (size_t)c * CHUNK;
    const float* src = xdbl + rowbase * 80 + DT_RANK;
    {                                         // CHUNK*8 == 256 float4s
        int i = threadIdx.x;
        int row = i >> 3, c4 = i & 7;
        *(float4*)&BC[row][c4 * 4] = *(const float4*)&src[(size_t)row * 80 + c4 * 4];
    }
    __syncthreads();
    float Av[16];
#pragma unroll
    for (int q = 0; q < 4; q++) {
        float4 a4 = *(const float4*)&A_log[(size_t)d * 16 + q * 4];
        Av[q * 4 + 0] = -__expf(a4.x) * LOG2E;
        Av[q * 4 + 1] = -__expf(a4.y) * LOG2E;
        Av[q * 4 + 2] = -__expf(a4.z) * LOG2E;
        Av[q * 4 + 3] = -__expf(a4.w) * LOG2E;
    }
    float Dd = Dp[d];
    float h[16];
    size_t gi = ((size_t)(b * NCHUNK + c) * D_INNER + d) * 16;
#pragma unroll
    for (int q = 0; q < 4; q++) {
        float4 c4v = *(const float4*)&carry[gi + q * 4];
        h[q * 4 + 0] = c4v.x; h[q * 4 + 1] = c4v.y;
        h[q * 4 + 2] = c4v.z; h[q * 4 + 3] = c4v.w;
    }
    const bf16_t* dtp = dtb + rowbase * D_INNER + d;
    const bf16_t* xp  = xi + rowbase * D_INNER + d;
    const bf16_t* zp  = xz + rowbase * (2 * D_INNER) + D_INNER + d;
    bf16_t* yp = yb + rowbase * D_INNER + d;
    bf16_t dt_n = dtp[0], x_n = xp[0], z_n = zp[0];
    for (int l = 0; l < CHUNK; l++) {
        float dt_c = __bfloat162float(dt_n), x_c = __bfloat162float(x_n);
        float z_c = __bfloat162float(z_n);
        if (l + 1 < CHUNK) {
            dt_n = dtp[(size_t)(l + 1) * D_INNER];
            x_n  = xp[(size_t)(l + 1) * D_INNER];
            z_n  = zp[(size_t)(l + 1) * (2 * D_INNER)];
        }
        float4 b0 = *(const float4*)&BC[l][0];
        float4 b1 = *(const float4*)&BC[l][4];
        float4 b2 = *(const float4*)&BC[l][8];
        float4 b3 = *(const float4*)&BC[l][12];
        float4 c0 = *(const float4*)&BC[l][16];
        float4 c1 = *(const float4*)&BC[l][20];
        float4 c2 = *(const float4*)&BC[l][24];
        float4 c3 = *(const float4*)&BC[l][28];
        float Bv[16] = {b0.x, b0.y, b0.z, b0.w, b1.x, b1.y, b1.z, b1.w,
                        b2.x, b2.y, b2.z, b2.w, b3.x, b3.y, b3.z, b3.w};
        float Cv[16] = {c0.x, c0.y, c0.z, c0.w, c1.x, c1.y, c1.z, c1.w,
                        c2.x, c2.y, c2.z, c2.w, c3.x, c3.y, c3.z, c3.w};
        float dtx = dt_c * x_c;
        float p = Dd * x_c;
#pragma unroll
        for (int s = 0; s < 16; s++) {
            h[s] = h[s] * EXP2F(dt_c * Av[s]) + dtx * Bv[s];
            p += h[s] * Cv[s];
        }
        yp[(size_t)l * D_INNER] = __float2bfloat16(p * siluf(z_c));
    }
}

// ----------------------------------------------------------------- launch ---
extern "C" void kernel_launch(void* const* d_in, const int* in_sizes, int n_in,
                              void* d_out, int out_size, void* d_ws, size_t ws_size,
                              hipStream_t stream) {
    const float* seq    = (const float*)d_in[0];
    const float* normw  = (const float*)d_in[1];
    const float* inpw   = (const float*)d_in[2];
    const float* convw  = (const float*)d_in[3];
    const float* convb  = (const float*)d_in[4];
    const float* xprojw = (const float*)d_in[5];
    const float* dtpw   = (const float*)d_in[6];
    const float* dtbias = (const float*)d_in[7];
    const float* Alog   = (const float*)d_in[8];
    const float* Dp     = (const float*)d_in[9];
    const float* outpw  = (const float*)d_in[10];
    float* out = (float*)d_out;

    float* ws = (float*)d_ws;
    float* xdbl  = ws;                        // 655360 f
    float* hend  = xdbl + 655360;             // 4*64*1536*16 = 6291456 f
    float* carry = hend + 6291456;            // 6291456 f
    float* dtsum = carry + 6291456;           // 4*64*1536 = 393216 f
    bf16_t* xi_bf    = (bf16_t*)(dtsum + 393216);  // 8192*1536 = 12582912
    bf16_t* dt_bf    = xi_bf + 12582912;           // 12582912
    bf16_t* xz_bf    = dt_bf + 12582912;           // 8192*3072 = 25165824
    bf16_t* xnorm_bf = xz_bf + 25165824;           // 8192*768  = 6291456
    bf16_t* y_bf     = xnorm_bf + 6291456;         // 12582912
    bf16_t* w1t      = y_bf + 12582912;            // 3072*768  = 2359296
    bf16_t* w4t      = w1t + 2359296;              // 768*1536  = 1179648
    bf16_t* wxt      = w4t + 1179648;              // 80*1536   = 122880
    bf16_t* wdt      = wxt + 122880;               // 1536*64   = 98304
    bf16_t* dtlo     = wdt + 98304;                // 8192*64   = 524288

    // 1. RMSNorm (bf16 out)
    rmsnorm_k<<<NROWS, 256, 0, stream>>>(seq, normw, xnorm_bf);

    // 1b. weight transposes -> bf16 [N][K]
    transpose_bf16_k<<<dim3(3072 / 32, 768 / 32), 256, 0, stream>>>(inpw, w1t, D_MODEL, 2 * D_INNER);
    transpose_bf16_k<<<dim3(768 / 32, 1536 / 32), 256, 0, stream>>>(outpw, w4t, D_INNER, D_MODEL);
    transpose_bf16_k<<<dim3(3, 1536 / 32), 256, 0, stream>>>(xprojw, wxt, D_INNER, 80);
    pad_dtw_k<<<(D_INNER * 64) / 256, 256, 0, stream>>>(dtpw, wdt);

    // zero xdbl for the split-K atomic accumulation
    hipMemsetAsync(xdbl, 0, (size_t)NROWS * 80 * sizeof(float), stream);

    // 2. in_proj (MFMA): xz_bf = xnorm @ in_proj_w   [8192 x 3072, K=768]
    mfma_gemm_k<3><<<dim3(3072 / 128, NROWS / 128), 256, 0, stream>>>(
        xnorm_bf, w1t, xz_bf, NROWS, 2 * D_INNER, D_MODEL, nullptr);

    // 3. depthwise conv + SiLU -> xi (bf16)
    conv_silu_k<<<(NROWS * D_INNER) / 256, 256, 0, stream>>>(xz_bf, convw, convb, xi_bf);

    // 4. x_proj (split-K MFMA, atomic): xdbl = xi @ x_proj_w  [8192 x 80, K=1536]
    xproj_k<<<dim3(NROWS / 64, XP_SPLIT), 256, 0, stream>>>(xi_bf, wxt, xdbl);

    // 5. dt_proj (MFMA, K padded 48->64) + softplus -> bf16 dt
    pad_dtlo_k<<<(NROWS * 64) / 256, 256, 0, stream>>>(xdbl, dtlo);
    mfma_gemm_k<5><<<dim3(D_INNER / 128, NROWS / 128), 256, 0, stream>>>(
        dtlo, wdt, dt_bf, NROWS, D_INNER, 64, dtbias);

    // 6. chunked selective scan (64 chunks of 32; exp2-native; bf16 dt/xi)
    scanA_k<<<dim3(D_INNER / 256, NCHUNK, NB), 256, 0, stream>>>(dt_bf, xi_bf, xdbl, Alog, hend, dtsum);
    scanB_k<<<(NB * D_INNER * 16) / 256, 256, 0, stream>>>(hend, dtsum, Alog, carry);
    scanC_k<<<dim3(D_INNER / 256, NCHUNK, NB), 256, 0, stream>>>(dt_bf, xi_bf, xdbl, xz_bf, Alog, Dp,
                                                                 carry, y_bf);

    // 7. out_proj (MFMA) + residual: out = y @ out_proj_w + seq
    mfma_gemm_k<2><<<dim3(D_MODEL / 128, NROWS / 128), 256, 0, stream>>>(
        y_bf, w4t, out, NROWS, D_MODEL, D_INNER, seq);
}

// Round 15
// 394.437 us; speedup vs baseline: 7.1095x; 1.0498x over previous
//
#include <hip/hip_runtime.h>
#include <hip/hip_bf16.h>
#include <cstdint>
#include <cstddef>

#define D_MODEL 768
#define D_STATE 16
#define D_CONV  4
#define D_INNER 1536
#define DT_RANK 48
#define NB      4
#define NL      2048
#define NROWS   (NB * NL)   // 8192
#define EPS     1e-5f
#define NCHUNK  64
#define CHUNK   (NL / NCHUNK)   // 32
#define XP_SPLIT 8
#define XP_KR   (D_INNER / XP_SPLIT)   // 192
#define LOG2E   1.44269504088896f

typedef __bf16 bf16x8 __attribute__((ext_vector_type(8)));
typedef float  f32x4  __attribute__((ext_vector_type(4)));
typedef __hip_bfloat16 bf16_t;

#if __has_builtin(__builtin_amdgcn_exp2f)
#define EXP2F(x) __builtin_amdgcn_exp2f(x)
#else
#define EXP2F(x) exp2f(x)
#endif

__device__ __forceinline__ float siluf(float x) { return x / (1.f + __expf(-x)); }
__device__ __forceinline__ float softplusf(float x) {
    return x > 20.f ? x : log1pf(__expf(x));
}
__device__ __forceinline__ void gload16(const void* g, void* l) {
    __builtin_amdgcn_global_load_lds((const __attribute__((address_space(1))) unsigned int*)g,
                                     (__attribute__((address_space(3))) unsigned int*)l, 16, 0, 0);
}

// ---------------------------------------------------------------- RMSNorm ---
__global__ __launch_bounds__(256) void rmsnorm_k(const float* __restrict__ seq,
                                                 const float* __restrict__ w,
                                                 bf16_t* __restrict__ out) {
    int row = blockIdx.x;
    const float* x = seq + (size_t)row * D_MODEL;
    bf16_t* o = out + (size_t)row * D_MODEL;
    int t = threadIdx.x;
    float v0 = x[t], v1 = x[t + 256], v2 = x[t + 512];
    float ss = v0 * v0 + v1 * v1 + v2 * v2;
#pragma unroll
    for (int off = 32; off; off >>= 1) ss += __shfl_down(ss, off, 64);
    __shared__ float parts[4];
    if ((t & 63) == 0) parts[t >> 6] = ss;
    __syncthreads();
    float tot = parts[0] + parts[1] + parts[2] + parts[3];
    float rs = rsqrtf(tot / (float)D_MODEL + EPS);
    o[t]       = __float2bfloat16(v0 * rs * w[t]);
    o[t + 256] = __float2bfloat16(v1 * rs * w[t + 256]);
    o[t + 512] = __float2bfloat16(v2 * rs * w[t + 512]);
}

// --------------------------------------------- weight transpose + convert ---
__global__ __launch_bounds__(256) void transpose_bf16_k(const float* __restrict__ w,
                                                        bf16_t* __restrict__ wt,
                                                        int K, int N) {
    __shared__ float t[32][33];
    int bx = blockIdx.x * 32, by = blockIdx.y * 32;
    int tx = threadIdx.x & 31, ty = threadIdx.x >> 5;
#pragma unroll
    for (int i = 0; i < 32; i += 8)
        if (bx + tx < N)
            t[ty + i][tx] = w[(size_t)(by + ty + i) * N + bx + tx];
    __syncthreads();
#pragma unroll
    for (int i = 0; i < 32; i += 8)
        if (bx + ty + i < N)
            wt[(size_t)(bx + ty + i) * K + by + tx] = __float2bfloat16(t[tx][ty + i]);
}

// -------------------------- dt_proj operand prep (pad K 48 -> 64, bf16) -----
__global__ __launch_bounds__(256) void pad_dtlo_k(const float* __restrict__ xdbl,
                                                  bf16_t* __restrict__ dtlo) {
    int idx = blockIdx.x * 256 + threadIdx.x;
    int row = idx >> 6, k = idx & 63;
    float v = (k < DT_RANK) ? xdbl[(size_t)row * 80 + k] : 0.f;
    dtlo[idx] = __float2bfloat16(v);
}
__global__ __launch_bounds__(256) void pad_dtw_k(const float* __restrict__ dtpw,
                                                 bf16_t* __restrict__ wdt) {
    int idx = blockIdx.x * 256 + threadIdx.x;   // n*64 + k
    int n = idx >> 6, k = idx & 63;
    float v = (k < DT_RANK) ? dtpw[(size_t)k * D_INNER + n] : 0.f;
    wdt[idx] = __float2bfloat16(v);
}

// ------------------------------------------------------- bf16 MFMA GEMM -----
// EPI 2: fp32 store acc + aux[row*N+col].  EPI 3: bf16 store.
// EPI 5: bf16 store softplus(acc + aux[col]).
template <int EPI>
__global__ __launch_bounds__(256) void mfma_gemm_k(const bf16_t* __restrict__ A,
                                                   const bf16_t* __restrict__ Bt,
                                                   void* __restrict__ Cv,
                                                   int M, int N, int K,
                                                   const float* __restrict__ aux) {
    __shared__ bf16_t As[128][64];
    __shared__ bf16_t Bs[128][64];
    const int tid = threadIdx.x;
    const int lane = tid & 63, wid = tid >> 6;
    const int bm = blockIdx.y * 128, bn = blockIdx.x * 128;
    const int wm = wid >> 1, wn = wid & 1;
    f32x4 acc[4][4] = {};
    for (int k0 = 0; k0 < K; k0 += 64) {
#pragma unroll
        for (int i = 0; i < 4; i++) {
            int idx = tid + i * 256;
            int r = idx >> 3, c = idx & 7;
            gload16(A + (size_t)(bm + r) * K + k0 + ((c ^ (r & 7)) << 3),
                    (bf16_t*)As + idx * 8);
        }
#pragma unroll
        for (int i = 0; i < 4; i++) {
            int idx = tid + i * 256;
            int r = idx >> 3, c = idx & 7;
            gload16(Bt + (size_t)(bn + r) * K + k0 + ((c ^ (r & 7)) << 3),
                    (bf16_t*)Bs + idx * 8);
        }
        asm volatile("s_waitcnt vmcnt(0)" ::: "memory");
        __syncthreads();
#pragma unroll
        for (int ks = 0; ks < 2; ks++) {
            bf16x8 af[4], bfr[4];
#pragma unroll
            for (int i = 0; i < 4; i++) {
                int row = wm * 64 + i * 16 + (lane & 15);
                int cl = ks * 4 + (lane >> 4);
                af[i] = *(const bf16x8*)(&As[row][(cl ^ (row & 7)) << 3]);
            }
#pragma unroll
            for (int j = 0; j < 4; j++) {
                int row = wn * 64 + j * 16 + (lane & 15);
                int cl = ks * 4 + (lane >> 4);
                bfr[j] = *(const bf16x8*)(&Bs[row][(cl ^ (row & 7)) << 3]);
            }
#pragma unroll
            for (int i = 0; i < 4; i++)
#pragma unroll
                for (int j = 0; j < 4; j++)
                    acc[i][j] = __builtin_amdgcn_mfma_f32_16x16x32_bf16(
                        af[i], bfr[j], acc[i][j], 0, 0, 0);
        }
        __syncthreads();
    }
#pragma unroll
    for (int i = 0; i < 4; i++) {
#pragma unroll
        for (int j = 0; j < 4; j++) {
#pragma unroll
            for (int q = 0; q < 4; q++) {
                int row = bm + wm * 64 + i * 16 + (lane >> 4) * 4 + q;
                int col = bn + wn * 64 + j * 16 + (lane & 15);
                float v = acc[i][j][q];
                if (EPI == 2) {
                    ((float*)Cv)[(size_t)row * N + col] = v + aux[(size_t)row * N + col];
                } else if (EPI == 5) {
                    ((bf16_t*)Cv)[(size_t)row * N + col] =
                        __float2bfloat16(softplusf(v + aux[col]));
                } else {
                    ((bf16_t*)Cv)[(size_t)row * N + col] = __float2bfloat16(v);
                }
            }
        }
    }
}

// --------------------------------------- x_proj: split-K skinny MFMA GEMM ---
__global__ __launch_bounds__(256) void xproj_k(const bf16_t* __restrict__ A,
                                               const bf16_t* __restrict__ Bt,
                                               float* __restrict__ C) {
    __shared__ bf16_t As[64][64];
    __shared__ bf16_t Bs[80][64];
    const int tid = threadIdx.x;
    const int lane = tid & 63, wid = tid >> 6;   // 4 waves
    const int bm = blockIdx.x * 64;
    const int k0base = blockIdx.y * XP_KR;
    f32x4 acc[5] = {};
    for (int kt = 0; kt < XP_KR; kt += 64) {
        int k0 = k0base + kt;
#pragma unroll
        for (int i = 0; i < 2; i++) {            // A: 512 chunks
            int idx = tid + i * 256;
            int r = idx >> 3, c = idx & 7;
            gload16(A + (size_t)(bm + r) * D_INNER + k0 + ((c ^ (r & 7)) << 3),
                    (bf16_t*)As + idx * 8);
        }
#pragma unroll
        for (int i = 0; i < 3; i++) {            // B: 640 chunks
            int idx = tid + i * 256;
            if (idx < 640) {
                int r = idx >> 3, c = idx & 7;
                gload16(Bt + (size_t)r * D_INNER + k0 + ((c ^ (r & 7)) << 3),
                        (bf16_t*)Bs + idx * 8);
            }
        }
        asm volatile("s_waitcnt vmcnt(0)" ::: "memory");
        __syncthreads();
#pragma unroll
        for (int ks = 0; ks < 2; ks++) {
            int arow = wid * 16 + (lane & 15);
            int cl = ks * 4 + (lane >> 4);
            bf16x8 af = *(const bf16x8*)(&As[arow][(cl ^ (arow & 7)) << 3]);
#pragma unroll
            for (int j = 0; j < 5; j++) {
                int brow = j * 16 + (lane & 15);
                bf16x8 bf_ = *(const bf16x8*)(&Bs[brow][(cl ^ (brow & 7)) << 3]);
                acc[j] = __builtin_amdgcn_mfma_f32_16x16x32_bf16(af, bf_, acc[j], 0, 0, 0);
            }
        }
        __syncthreads();
    }
#pragma unroll
    for (int j = 0; j < 5; j++)
#pragma unroll
        for (int q = 0; q < 4; q++) {
            int row = bm + wid * 16 + (lane >> 4) * 4 + q;
            int col = j * 16 + (lane & 15);
            atomicAdd(&C[(size_t)row * 80 + col], acc[j][q]);
        }
}

// -------------------------------- depthwise conv + SiLU (8-wide vectorized) -
// one thread per 8 consecutive channels: 4x 16B row loads, 16B store
__global__ __launch_bounds__(256) void conv_silu_k(const bf16_t* __restrict__ xz,
                                                   const float* __restrict__ cw,
                                                   const float* __restrict__ cb,
                                                   bf16_t* __restrict__ xi) {
    const int DI8 = D_INNER / 8;   // 192
    int idx = blockIdx.x * 256 + threadIdx.x;
    int d8 = (idx % DI8) * 8;
    int row = idx / DI8;           // b*NL + l
    int l = row % NL;
    const bf16_t* base = xz + (size_t)row * (2 * D_INNER) + d8;
    bf16x8 zero = {};
    bf16x8 r3 = *(const bf16x8*)base;                                   // l
    bf16x8 r2 = (l >= 1) ? *(const bf16x8*)(base - 2 * D_INNER) : zero; // l-1
    bf16x8 r1 = (l >= 2) ? *(const bf16x8*)(base - 4 * D_INNER) : zero; // l-2
    bf16x8 r0 = (l >= 3) ? *(const bf16x8*)(base - 6 * D_INNER) : zero; // l-3
    // weights: cw[d8*4 .. d8*4+31] contiguous; bias cb[d8..d8+7]
    f32x4 w[8];
#pragma unroll
    for (int i = 0; i < 8; i++) w[i] = *(const f32x4*)&cw[(size_t)(d8 + i) * 4];
    f32x4 b0 = *(const f32x4*)&cb[d8];
    f32x4 b1 = *(const f32x4*)&cb[d8 + 4];
    bf16x8 outv;
#pragma unroll
    for (int i = 0; i < 8; i++) {
        float bias = (i < 4) ? b0[i] : b1[i - 4];
        float acc = bias + w[i][0] * (float)r0[i] + w[i][1] * (float)r1[i]
                         + w[i][2] * (float)r2[i] + w[i][3] * (float)r3[i];
        outv[i] = (__bf16)siluf(acc);
    }
    *(bf16x8*)(xi + (size_t)row * D_INNER + d8) = outv;
}

// --------------------------------------------------- scan phase A: carries --
__global__ __launch_bounds__(256) void scanA_k(const bf16_t* __restrict__ dtb,
                                               const bf16_t* __restrict__ xi,
                                               const float* __restrict__ xdbl,
                                               const float* __restrict__ A_log,
                                               float* __restrict__ hend,
                                               float* __restrict__ dtsum) {
    __shared__ float Bsh[CHUNK][16];
    const int d = blockIdx.x * 256 + threadIdx.x;
    const int c = blockIdx.y, b = blockIdx.z;
    const size_t rowbase = (size_t)b * NL + (size_t)c * CHUNK;
    const float* bsrc = xdbl + rowbase * 80 + DT_RANK;
    if (threadIdx.x < CHUNK * 4) {            // 128 float4s
        int i = threadIdx.x;
        int row = i >> 2, c4 = i & 3;
        *(float4*)&Bsh[row][c4 * 4] = *(const float4*)&bsrc[(size_t)row * 80 + c4 * 4];
    }
    __syncthreads();
    float Av[16];
#pragma unroll
    for (int q = 0; q < 4; q++) {
        float4 a4 = *(const float4*)&A_log[(size_t)d * 16 + q * 4];
        Av[q * 4 + 0] = -__expf(a4.x) * LOG2E;
        Av[q * 4 + 1] = -__expf(a4.y) * LOG2E;
        Av[q * 4 + 2] = -__expf(a4.z) * LOG2E;
        Av[q * 4 + 3] = -__expf(a4.w) * LOG2E;
    }
    float h[16];
#pragma unroll
    for (int s = 0; s < 16; s++) h[s] = 0.f;
    float dts = 0.f;
    const bf16_t* dtp = dtb + rowbase * D_INNER + d;
    const bf16_t* xp  = xi + rowbase * D_INNER + d;
    bf16_t dt_n = dtp[0], x_n = xp[0];
    for (int l = 0; l < CHUNK; l++) {
        float dt_c = __bfloat162float(dt_n), x_c = __bfloat162float(x_n);
        if (l + 1 < CHUNK) {
            dt_n = dtp[(size_t)(l + 1) * D_INNER];
            x_n  = xp[(size_t)(l + 1) * D_INNER];
        }
        float4 b0 = *(const float4*)&Bsh[l][0];
        float4 b1 = *(const float4*)&Bsh[l][4];
        float4 b2 = *(const float4*)&Bsh[l][8];
        float4 b3 = *(const float4*)&Bsh[l][12];
        float Bv[16] = {b0.x, b0.y, b0.z, b0.w, b1.x, b1.y, b1.z, b1.w,
                        b2.x, b2.y, b2.z, b2.w, b3.x, b3.y, b3.z, b3.w};
        float dtx = dt_c * x_c;
#pragma unroll
        for (int s = 0; s < 16; s++)
            h[s] = h[s] * EXP2F(dt_c * Av[s]) + dtx * Bv[s];
        dts += dt_c;
    }
    size_t gi = ((size_t)(b * NCHUNK + c) * D_INNER + d) * 16;
#pragma unroll
    for (int q = 0; q < 4; q++)
        *(float4*)&hend[gi + q * 4] =
            make_float4(h[q * 4], h[q * 4 + 1], h[q * 4 + 2], h[q * 4 + 3]);
    dtsum[gi >> 4] = dts;
}

// --------------------------------------------- scan phase B: combine carries -
__global__ __launch_bounds__(256) void scanB_k(const float* __restrict__ hend,
                                               const float* __restrict__ dtsum,
                                               const float* __restrict__ A_log,
                                               float* __restrict__ carry) {
    int t = blockIdx.x * 256 + threadIdx.x;   // (b*D_INNER+d)*16+s
    int s = t & 15;
    int bd = t >> 4;
    int b = bd / D_INNER, d = bd % D_INNER;
    float Av2 = -__expf(A_log[d * D_STATE + s]) * LOG2E;
    float h = 0.f;
    for (int c = 0; c < NCHUNK; c++) {
        size_t gi = (size_t)(b * NCHUNK + c) * D_INNER + d;
        carry[gi * 16 + s] = h;
        h = h * EXP2F(Av2 * dtsum[gi]) + hend[gi * 16 + s];
    }
}

// ------------------------------- scan phase C: full scan + gating, y -> bf16 -
__global__ __launch_bounds__(256) void scanC_k(const bf16_t* __restrict__ dtb,
                                               const bf16_t* __restrict__ xi,
                                               const float* __restrict__ xdbl,
                                               const bf16_t* __restrict__ xz,
                                               const float* __restrict__ A_log,
                                               const float* __restrict__ Dp,
                                               const float* __restrict__ carry,
                                               bf16_t* __restrict__ yb) {
    __shared__ float BC[CHUNK][32];
    const int d = blockIdx.x * 256 + threadIdx.x;
    const int c = blockIdx.y, b = blockIdx.z;
    const size_t rowbase = (size_t)b * NL + (size_t)c * CHUNK;
    const float* src = xdbl + rowbase * 80 + DT_RANK;
    {                                         // CHUNK*8 == 256 float4s
        int i = threadIdx.x;
        int row = i >> 3, c4 = i & 7;
        *(float4*)&BC[row][c4 * 4] = *(const float4*)&src[(size_t)row * 80 + c4 * 4];
    }
    __syncthreads();
    float Av[16];
#pragma unroll
    for (int q = 0; q < 4; q++) {
        float4 a4 = *(const float4*)&A_log[(size_t)d * 16 + q * 4];
        Av[q * 4 + 0] = -__expf(a4.x) * LOG2E;
        Av[q * 4 + 1] = -__expf(a4.y) * LOG2E;
        Av[q * 4 + 2] = -__expf(a4.z) * LOG2E;
        Av[q * 4 + 3] = -__expf(a4.w) * LOG2E;
    }
    float Dd = Dp[d];
    float h[16];
    size_t gi = ((size_t)(b * NCHUNK + c) * D_INNER + d) * 16;
#pragma unroll
    for (int q = 0; q < 4; q++) {
        float4 c4v = *(const float4*)&carry[gi + q * 4];
        h[q * 4 + 0] = c4v.x; h[q * 4 + 1] = c4v.y;
        h[q * 4 + 2] = c4v.z; h[q * 4 + 3] = c4v.w;
    }
    const bf16_t* dtp = dtb + rowbase * D_INNER + d;
    const bf16_t* xp  = xi + rowbase * D_INNER + d;
    const bf16_t* zp  = xz + rowbase * (2 * D_INNER) + D_INNER + d;
    bf16_t* yp = yb + rowbase * D_INNER + d;
    bf16_t dt_n = dtp[0], x_n = xp[0], z_n = zp[0];
    for (int l = 0; l < CHUNK; l++) {
        float dt_c = __bfloat162float(dt_n), x_c = __bfloat162float(x_n);
        float z_c = __bfloat162float(z_n);
        if (l + 1 < CHUNK) {
            dt_n = dtp[(size_t)(l + 1) * D_INNER];
            x_n  = xp[(size_t)(l + 1) * D_INNER];
            z_n  = zp[(size_t)(l + 1) * (2 * D_INNER)];
        }
        float4 b0 = *(const float4*)&BC[l][0];
        float4 b1 = *(const float4*)&BC[l][4];
        float4 b2 = *(const float4*)&BC[l][8];
        float4 b3 = *(const float4*)&BC[l][12];
        float4 c0 = *(const float4*)&BC[l][16];
        float4 c1 = *(const float4*)&BC[l][20];
        float4 c2 = *(const float4*)&BC[l][24];
        float4 c3 = *(const float4*)&BC[l][28];
        float Bv[16] = {b0.x, b0.y, b0.z, b0.w, b1.x, b1.y, b1.z, b1.w,
                        b2.x, b2.y, b2.z, b2.w, b3.x, b3.y, b3.z, b3.w};
        float Cv[16] = {c0.x, c0.y, c0.z, c0.w, c1.x, c1.y, c1.z, c1.w,
                        c2.x, c2.y, c2.z, c2.w, c3.x, c3.y, c3.z, c3.w};
        float dtx = dt_c * x_c;
        float p = Dd * x_c;
#pragma unroll
        for (int s = 0; s < 16; s++) {
            h[s] = h[s] * EXP2F(dt_c * Av[s]) + dtx * Bv[s];
            p += h[s] * Cv[s];
        }
        yp[(size_t)l * D_INNER] = __float2bfloat16(p * siluf(z_c));
    }
}

// ----------------------------------------------------------------- launch ---
extern "C" void kernel_launch(void* const* d_in, const int* in_sizes, int n_in,
                              void* d_out, int out_size, void* d_ws, size_t ws_size,
                              hipStream_t stream) {
    const float* seq    = (const float*)d_in[0];
    const float* normw  = (const float*)d_in[1];
    const float* inpw   = (const float*)d_in[2];
    const float* convw  = (const float*)d_in[3];
    const float* convb  = (const float*)d_in[4];
    const float* xprojw = (const float*)d_in[5];
    const float* dtpw   = (const float*)d_in[6];
    const float* dtbias = (const float*)d_in[7];
    const float* Alog   = (const float*)d_in[8];
    const float* Dp     = (const float*)d_in[9];
    const float* outpw  = (const float*)d_in[10];
    float* out = (float*)d_out;

    float* ws = (float*)d_ws;
    float* xdbl  = ws;                        // 655360 f
    float* hend  = xdbl + 655360;             // 4*64*1536*16 = 6291456 f
    float* carry = hend + 6291456;            // 6291456 f
    float* dtsum = carry + 6291456;           // 4*64*1536 = 393216 f
    bf16_t* xi_bf    = (bf16_t*)(dtsum + 393216);  // 8192*1536 = 12582912
    bf16_t* dt_bf    = xi_bf + 12582912;           // 12582912
    bf16_t* xz_bf    = dt_bf + 12582912;           // 8192*3072 = 25165824
    bf16_t* xnorm_bf = xz_bf + 25165824;           // 8192*768  = 6291456
    bf16_t* y_bf     = xnorm_bf + 6291456;         // 12582912
    bf16_t* w1t      = y_bf + 12582912;            // 3072*768  = 2359296
    bf16_t* w4t      = w1t + 2359296;              // 768*1536  = 1179648
    bf16_t* wxt      = w4t + 1179648;              // 80*1536   = 122880
    bf16_t* wdt      = wxt + 122880;               // 1536*64   = 98304
    bf16_t* dtlo     = wdt + 98304;                // 8192*64   = 524288

    // 1. RMSNorm (bf16 out)
    rmsnorm_k<<<NROWS, 256, 0, stream>>>(seq, normw, xnorm_bf);

    // 1b. weight transposes -> bf16 [N][K]
    transpose_bf16_k<<<dim3(3072 / 32, 768 / 32), 256, 0, stream>>>(inpw, w1t, D_MODEL, 2 * D_INNER);
    transpose_bf16_k<<<dim3(768 / 32, 1536 / 32), 256, 0, stream>>>(outpw, w4t, D_INNER, D_MODEL);
    transpose_bf16_k<<<dim3(3, 1536 / 32), 256, 0, stream>>>(xprojw, wxt, D_INNER, 80);
    pad_dtw_k<<<(D_INNER * 64) / 256, 256, 0, stream>>>(dtpw, wdt);

    // zero xdbl for the split-K atomic accumulation
    hipMemsetAsync(xdbl, 0, (size_t)NROWS * 80 * sizeof(float), stream);

    // 2. in_proj (MFMA): xz_bf = xnorm @ in_proj_w   [8192 x 3072, K=768]
    mfma_gemm_k<3><<<dim3(3072 / 128, NROWS / 128), 256, 0, stream>>>(
        xnorm_bf, w1t, xz_bf, NROWS, 2 * D_INNER, D_MODEL, nullptr);

    // 3. depthwise conv + SiLU -> xi (bf16, 8-wide vectorized)
    conv_silu_k<<<(NROWS * (D_INNER / 8)) / 256, 256, 0, stream>>>(xz_bf, convw, convb, xi_bf);

    // 4. x_proj (split-K MFMA, atomic): xdbl = xi @ x_proj_w  [8192 x 80, K=1536]
    xproj_k<<<dim3(NROWS / 64, XP_SPLIT), 256, 0, stream>>>(xi_bf, wxt, xdbl);

    // 5. dt_proj (MFMA, K padded 48->64) + softplus -> bf16 dt
    pad_dtlo_k<<<(NROWS * 64) / 256, 256, 0, stream>>>(xdbl, dtlo);
    mfma_gemm_k<5><<<dim3(D_INNER / 128, NROWS / 128), 256, 0, stream>>>(
        dtlo, wdt, dt_bf, NROWS, D_INNER, 64, dtbias);

    // 6. chunked selective scan (64 chunks of 32; exp2-native; bf16 dt/xi)
    scanA_k<<<dim3(D_INNER / 256, NCHUNK, NB), 256, 0, stream>>>(dt_bf, xi_bf, xdbl, Alog, hend, dtsum);
    scanB_k<<<(NB * D_INNER * 16) / 256, 256, 0, stream>>>(hend, dtsum, Alog, carry);
    scanC_k<<<dim3(D_INNER / 256, NCHUNK, NB), 256, 0, stream>>>(dt_bf, xi_bf, xdbl, xz_bf, Alog, Dp,
                                                                 carry, y_bf);

    // 7. out_proj (MFMA) + residual: out = y @ out_proj_w + seq
    mfma_gemm_k<2><<<dim3(D_MODEL / 128, NROWS / 128), 256, 0, stream>>>(
        y_bf, w4t, out, NROWS, D_MODEL, D_INNER, seq);
}